// Round 1
// baseline (867.286 us; speedup 1.0000x reference)
//
#include <hip/hip_runtime.h>

#define NH 16
#define DMODEL 1024
#define DK 64
#define DV 64
#define BB 4
#define SS 2048
#define NTOK (BB*SS)
#define LN_EPS 1e-5f

typedef __attribute__((ext_vector_type(4))) float f32x4;
typedef __attribute__((ext_vector_type(8))) short s16x8;
typedef __attribute__((ext_vector_type(4))) short s16x4;

__device__ __forceinline__ short f2bf(float f) {
    union { float f; unsigned u; } a; a.f = f;
    unsigned r = a.u + 0x7FFFu + ((a.u >> 16) & 1u);
    return (short)(r >> 16);
}

// ---------------- K0: conversions ----------------
__global__ void k_cast_x(const float* __restrict__ x, short* __restrict__ xb) {
    int i = blockIdx.x * blockDim.x + threadIdx.x;      // one float4 per thread
    f32x4 v = reinterpret_cast<const f32x4*>(x)[i];
    s16x4 o;
    o[0] = f2bf(v[0]); o[1] = f2bf(v[1]); o[2] = f2bf(v[2]); o[3] = f2bf(v[3]);
    reinterpret_cast<s16x4*>(xb)[i] = o;
}

// WT[n][d], n in [0,3072): 0..1023 Q-heads, 1024..2047 K, 2048..3071 V
__global__ void k_conv_wqkv(const float* __restrict__ Wq, const float* __restrict__ Wk,
                            const float* __restrict__ Wv, short* __restrict__ WT) {
    int idx = blockIdx.x * blockDim.x + threadIdx.x;    // 3072*1024 threads
    int n = idx >> 10, d = idx & 1023;
    const float* src = Wq; int nn = n;
    if (n >= 2048)      { src = Wv; nn = n - 2048; }
    else if (n >= 1024) { src = Wk; nn = n - 1024; }
    int h = nn >> 6, kk = nn & 63;
    WT[idx] = f2bf(src[(h * DMODEL + d) * DK + kk]);
}

// WfcT[dout][c] = Wfc[c][dout]
__global__ void k_conv_wfc(const float* __restrict__ Wfc, short* __restrict__ WfcT) {
    int idx = blockIdx.x * blockDim.x + threadIdx.x;    // 1024*1024 threads
    int n = idx >> 10, c = idx & 1023;
    WfcT[idx] = f2bf(Wfc[c * 1024 + n]);
}

// ---------------- GEMM: C[M,N] = A[M,1024] * BT[N,1024]^T ----------------
// MODE 0: QKV projection (N=3072), scatter to Qb/Kb/Vb bf16 with bias (+scale on Q)
// MODE 1: FC (N=1024), write fp32 Y with bias bfc
template<int MODE>
__global__ __launch_bounds__(256) void k_gemm(const short* __restrict__ A,
                                              const short* __restrict__ BT,
                                              const float* __restrict__ bq,
                                              const float* __restrict__ bk,
                                              const float* __restrict__ bv,
                                              const float* __restrict__ bfc,
                                              short* __restrict__ Qb,
                                              short* __restrict__ Kb,
                                              short* __restrict__ Vb,
                                              float* __restrict__ Y) {
    __shared__ short sA[128][32];
    __shared__ short sB[128][32];
    const int gm0 = blockIdx.y * 128, gn0 = blockIdx.x * 128;
    const int t = threadIdx.x;
    const int lane = t & 63, w = t >> 6;
    const int wm = w >> 1, wn = w & 1;
    const int lr = lane & 15, lg = lane >> 4;

    f32x4 acc[4][4] = {};

    const int r = t >> 1, hh = (t & 1) * 16;
    const short* pa = A  + (size_t)(gm0 + r) * 1024 + hh;
    const short* pb = BT + (size_t)(gn0 + r) * 1024 + hh;

    for (int k0 = 0; k0 < 1024; k0 += 32) {
        *reinterpret_cast<s16x8*>(&sA[r][hh])     = *reinterpret_cast<const s16x8*>(pa + k0);
        *reinterpret_cast<s16x8*>(&sA[r][hh + 8]) = *reinterpret_cast<const s16x8*>(pa + k0 + 8);
        *reinterpret_cast<s16x8*>(&sB[r][hh])     = *reinterpret_cast<const s16x8*>(pb + k0);
        *reinterpret_cast<s16x8*>(&sB[r][hh + 8]) = *reinterpret_cast<const s16x8*>(pb + k0 + 8);
        __syncthreads();
        s16x8 aF[4], bF[4];
        #pragma unroll
        for (int i = 0; i < 4; i++) aF[i] = *reinterpret_cast<const s16x8*>(&sA[wm * 64 + i * 16 + lr][lg * 8]);
        #pragma unroll
        for (int i = 0; i < 4; i++) bF[i] = *reinterpret_cast<const s16x8*>(&sB[wn * 64 + i * 16 + lr][lg * 8]);
        #pragma unroll
        for (int i = 0; i < 4; i++)
            #pragma unroll
            for (int j = 0; j < 4; j++)
                acc[i][j] = __builtin_amdgcn_mfma_f32_16x16x32_bf16(aF[i], bF[j], acc[i][j], 0, 0, 0);
        __syncthreads();
    }

    #pragma unroll
    for (int i = 0; i < 4; i++) {
        #pragma unroll
        for (int j = 0; j < 4; j++) {
            #pragma unroll
            for (int rg = 0; rg < 4; rg++) {
                int m = gm0 + wm * 64 + i * 16 + lg * 4 + rg;
                int n = gn0 + wn * 64 + j * 16 + lr;
                float val = acc[i][j][rg];
                if (MODE == 0) {
                    int b = m >> 11, s = m & 2047;
                    if (n < 1024) {
                        int h = n >> 6, kk = n & 63;
                        val = (val + bq[n]) * 0.18033688011112042f;  // (1/8)*log2(e)
                        Qb[((size_t)(b * NH + h) * SS + s) * DK + kk] = f2bf(val);
                    } else if (n < 2048) {
                        int n2 = n - 1024; int h = n2 >> 6, kk = n2 & 63;
                        Kb[((size_t)(b * NH + h) * SS + s) * DK + kk] = f2bf(val + bk[n2]);
                    } else {
                        int n2 = n - 2048; int h = n2 >> 6, kk = n2 & 63;
                        Vb[((size_t)(b * NH + h) * SS + s) * DK + kk] = f2bf(val + bv[n2]);
                    }
                } else {
                    Y[(size_t)m * 1024 + n] = val + bfc[n];
                }
            }
        }
    }
}

// ---------------- V transpose: [bh][S][64] -> [bh][64][S] ----------------
__global__ __launch_bounds__(256) void k_transpose_v(const short* __restrict__ Vb,
                                                     short* __restrict__ VT) {
    __shared__ short tile[64][65];
    const int bh = blockIdx.y, s0 = blockIdx.x * 64;
    const short* src = Vb + ((size_t)bh * SS + s0) * 64;
    short* dst = VT + (size_t)bh * 64 * SS;
    const int t = threadIdx.x;
    {
        int r = t >> 2, c0 = (t & 3) * 16;
        s16x8 v0 = *reinterpret_cast<const s16x8*>(&src[r * 64 + c0]);
        s16x8 v1 = *reinterpret_cast<const s16x8*>(&src[r * 64 + c0 + 8]);
        #pragma unroll
        for (int i = 0; i < 8; i++) { tile[r][c0 + i] = v0[i]; tile[r][c0 + 8 + i] = v1[i]; }
    }
    __syncthreads();
    {
        int vv = t >> 2, so = (t & 3) * 16;
        s16x8 o0, o1;
        #pragma unroll
        for (int i = 0; i < 8; i++) { o0[i] = tile[so + i][vv]; o1[i] = tile[so + 8 + i][vv]; }
        *reinterpret_cast<s16x8*>(&dst[(size_t)vv * SS + s0 + so])     = o0;
        *reinterpret_cast<s16x8*>(&dst[(size_t)vv * SS + s0 + so + 8]) = o1;
    }
}

// ---------------- Flash attention (swapped QK^T), per wave: 16 q-rows ----------------
__global__ __launch_bounds__(256) void k_attn(const short* __restrict__ Qb,
                                              const short* __restrict__ Kb,
                                              const short* __restrict__ VT,
                                              short* __restrict__ cat) {
    const int qt = blockIdx.x;        // q tile of 64
    const int bh = blockIdx.y;        // b*16+h
    const int b = bh >> 4, h = bh & 15;
    const int t = threadIdx.x, lane = t & 63, w = t >> 6;
    const int lr = lane & 15, lg = lane >> 4;
    const int q = qt * 64 + w * 16 + lr;

    const short* Qrow = Qb + ((size_t)bh * SS + q) * DK;
    s16x8 qF0 = *reinterpret_cast<const s16x8*>(&Qrow[lg * 8]);
    s16x8 qF1 = *reinterpret_cast<const s16x8*>(&Qrow[32 + lg * 8]);
    const short* Kbase = Kb + (size_t)bh * SS * DK;
    const short* Vbase = VT + (size_t)bh * DK * SS;

    f32x4 acc[4] = {};
    float mrun = -1e30f, ssum = 0.f;

    for (int kt = 0; kt < SS; kt += 32) {
        const short* K0 = Kbase + (size_t)(kt + lr) * DK;
        const short* K1 = Kbase + (size_t)(kt + 16 + lr) * DK;
        s16x8 kA00 = *reinterpret_cast<const s16x8*>(&K0[lg * 8]);
        s16x8 kA01 = *reinterpret_cast<const s16x8*>(&K0[32 + lg * 8]);
        s16x8 kA10 = *reinterpret_cast<const s16x8*>(&K1[lg * 8]);
        s16x8 kA11 = *reinterpret_cast<const s16x8*>(&K1[32 + lg * 8]);
        f32x4 st0 = {}, st1 = {};
        st0 = __builtin_amdgcn_mfma_f32_16x16x32_bf16(kA00, qF0, st0, 0, 0, 0);
        st0 = __builtin_amdgcn_mfma_f32_16x16x32_bf16(kA01, qF1, st0, 0, 0, 0);
        st1 = __builtin_amdgcn_mfma_f32_16x16x32_bf16(kA10, qF0, st1, 0, 0, 0);
        st1 = __builtin_amdgcn_mfma_f32_16x16x32_bf16(kA11, qF1, st1, 0, 0, 0);

        // online softmax over the 32 keys (scores pre-scaled to log2 domain)
        float tmax = fmaxf(fmaxf(fmaxf(st0[0], st0[1]), fmaxf(st0[2], st0[3])),
                           fmaxf(fmaxf(st1[0], st1[1]), fmaxf(st1[2], st1[3])));
        tmax = fmaxf(tmax, __shfl_xor(tmax, 16));
        tmax = fmaxf(tmax, __shfl_xor(tmax, 32));
        float mnew = fmaxf(mrun, tmax);
        float alpha = exp2f(mrun - mnew);
        float p0[4], p1[4];
        float tsum = 0.f;
        #pragma unroll
        for (int r2 = 0; r2 < 4; r2++) {
            p0[r2] = exp2f(st0[r2] - mnew);
            p1[r2] = exp2f(st1[r2] - mnew);
            tsum += p0[r2] + p1[r2];
        }
        tsum += __shfl_xor(tsum, 16);
        tsum += __shfl_xor(tsum, 32);
        ssum = ssum * alpha + tsum;
        mrun = mnew;

        s16x8 pb;
        pb[0] = f2bf(p0[0]); pb[1] = f2bf(p0[1]); pb[2] = f2bf(p0[2]); pb[3] = f2bf(p0[3]);
        pb[4] = f2bf(p1[0]); pb[5] = f2bf(p1[1]); pb[6] = f2bf(p1[2]); pb[7] = f2bf(p1[3]);

        #pragma unroll
        for (int vt = 0; vt < 4; vt++) {
            const short* Vp = Vbase + (size_t)(vt * 16 + lr) * SS + kt + lg * 4;
            s16x4 va = *reinterpret_cast<const s16x4*>(Vp);
            s16x4 vb2 = *reinterpret_cast<const s16x4*>(Vp + 16);
            s16x8 vA;
            vA[0] = va[0]; vA[1] = va[1]; vA[2] = va[2]; vA[3] = va[3];
            vA[4] = vb2[0]; vA[5] = vb2[1]; vA[6] = vb2[2]; vA[7] = vb2[3];
            #pragma unroll
            for (int r2 = 0; r2 < 4; r2++) acc[vt][r2] *= alpha;
            acc[vt] = __builtin_amdgcn_mfma_f32_16x16x32_bf16(vA, pb, acc[vt], 0, 0, 0);
        }
    }

    float inv = 1.0f / ssum;
    __shared__ short ods[4][16][64];
    #pragma unroll
    for (int vt = 0; vt < 4; vt++)
        #pragma unroll
        for (int rg = 0; rg < 4; rg++)
            ods[w][lr][vt * 16 + lg * 4 + rg] = f2bf(acc[vt][rg] * inv);
    __syncthreads();
    {
        int qr = lane >> 2, c0 = (lane & 3) * 16;
        s16x8 o0 = *reinterpret_cast<const s16x8*>(&ods[w][qr][c0]);
        s16x8 o1 = *reinterpret_cast<const s16x8*>(&ods[w][qr][c0 + 8]);
        int token = b * SS + qt * 64 + w * 16 + qr;
        short* dst = cat + (size_t)token * (NH * DV) + h * DV + c0;
        *reinterpret_cast<s16x8*>(dst) = o0;
        *reinterpret_cast<s16x8*>(dst + 8) = o1;
    }
}

// ---------------- LayerNorm ----------------
__global__ __launch_bounds__(256) void k_ln(const float* __restrict__ Y,
                                            const float* __restrict__ gamma,
                                            const float* __restrict__ beta,
                                            float* __restrict__ out) {
    const int row = blockIdx.x;
    const int t = threadIdx.x;
    const float* y = Y + (size_t)row * 1024;
    f32x4 v = reinterpret_cast<const f32x4*>(y)[t];
    float s = v[0] + v[1] + v[2] + v[3];
    float s2 = v[0] * v[0] + v[1] * v[1] + v[2] * v[2] + v[3] * v[3];
    #pragma unroll
    for (int off = 32; off; off >>= 1) {
        s += __shfl_xor(s, off);
        s2 += __shfl_xor(s2, off);
    }
    __shared__ float red[8];
    int w = t >> 6, lane = t & 63;
    if (lane == 0) { red[w] = s; red[4 + w] = s2; }
    __syncthreads();
    float S = red[0] + red[1] + red[2] + red[3];
    float S2 = red[4] + red[5] + red[6] + red[7];
    float mu = S * (1.f / 1024.f);
    float var = S2 * (1.f / 1024.f) - mu * mu;
    float rs = rsqrtf(var + LN_EPS);
    f32x4 g = reinterpret_cast<const f32x4*>(gamma)[t];
    f32x4 be = reinterpret_cast<const f32x4*>(beta)[t];
    f32x4 o;
    #pragma unroll
    for (int i = 0; i < 4; i++) o[i] = (v[i] - mu) * rs * g[i] + be[i];
    reinterpret_cast<f32x4*>(out + (size_t)row * 1024)[t] = o;
}

// ---------------- launch ----------------
extern "C" void kernel_launch(void* const* d_in, const int* in_sizes, int n_in,
                              void* d_out, int out_size, void* d_ws, size_t ws_size,
                              hipStream_t stream) {
    const float* x    = (const float*)d_in[0];
    const float* Wq   = (const float*)d_in[1];
    const float* bq   = (const float*)d_in[2];
    const float* Wk   = (const float*)d_in[3];
    const float* bk   = (const float*)d_in[4];
    const float* Wv   = (const float*)d_in[5];
    const float* bv   = (const float*)d_in[6];
    const float* Wfc  = (const float*)d_in[7];
    const float* bfc  = (const float*)d_in[8];
    const float* gamma= (const float*)d_in[9];
    const float* beta = (const float*)d_in[10];
    float* out = (float*)d_out;

    char* p = (char*)d_ws;
    short* xb   = (short*)p; p += (size_t)NTOK * 1024 * 2;      // 16.8 MB
    short* WT   = (short*)p; p += (size_t)3072 * 1024 * 2;      //  6.3 MB
    short* WfcT = (short*)p; p += (size_t)1024 * 1024 * 2;      //  2.1 MB
    short* Qb   = (short*)p; p += (size_t)64 * SS * 64 * 2;     // 16.8 MB
    short* Kb   = (short*)p; p += (size_t)64 * SS * 64 * 2;     // 16.8 MB
    short* Vb   = (short*)p; p += (size_t)64 * SS * 64 * 2;     // 16.8 MB
    short* VTb  = (short*)p; p += (size_t)64 * 64 * SS * 2;     // 16.8 MB
    short* cat  = (short*)p; p += (size_t)NTOK * 1024 * 2;      // 16.8 MB
    float* Y    = (float*)Qb;  // aliases Qb+Kb (dead after k_attn): 33.5 MB

    k_cast_x   <<<NTOK * 1024 / 4 / 256, 256, 0, stream>>>(x, xb);
    k_conv_wqkv<<<3072 * 1024 / 256, 256, 0, stream>>>(Wq, Wk, Wv, WT);
    k_conv_wfc <<<1024 * 1024 / 256, 256, 0, stream>>>(Wfc, WfcT);
    k_gemm<0>  <<<dim3(24, 64), 256, 0, stream>>>(xb, WT, bq, bk, bv, nullptr, Qb, Kb, Vb, nullptr);
    k_transpose_v<<<dim3(SS / 64, 64), 256, 0, stream>>>(Vb, VTb);
    k_attn     <<<dim3(SS / 64, 64), 256, 0, stream>>>(Qb, Kb, VTb, cat);
    k_gemm<1>  <<<dim3(8, 64), 256, 0, stream>>>(cat, WfcT, nullptr, nullptr, nullptr, bfc, nullptr, nullptr, nullptr, Y);
    k_ln       <<<NTOK, 256, 0, stream>>>(Y, gamma, beta, out);
}

// Round 2
// 343.266 us; speedup vs baseline: 2.5266x; 2.5266x over previous
//
#include <hip/hip_runtime.h>

#define NH 16
#define DMODEL 1024
#define DK 64
#define DV 64
#define BB 4
#define SS 2048
#define NTOK (BB*SS)
#define LN_EPS 1e-5f

typedef __attribute__((ext_vector_type(4))) float f32x4;
typedef __attribute__((ext_vector_type(8))) short s16x8;
typedef __attribute__((ext_vector_type(4))) short s16x4;

__device__ __forceinline__ short f2bf(float f) {
    union { float f; unsigned u; } a; a.f = f;
    unsigned r = a.u + 0x7FFFu + ((a.u >> 16) & 1u);
    return (short)(r >> 16);
}
// cheap round-half-up: fine for P in [0,256]
__device__ __forceinline__ short f2bf_fast(float f) {
    union { float f; unsigned u; } a; a.f = f;
    return (short)((a.u + 0x8000u) >> 16);
}
__device__ __forceinline__ void gll16(const void* g, void* l) {
    __builtin_amdgcn_global_load_lds(
        (const __attribute__((address_space(1))) unsigned int*)g,
        (__attribute__((address_space(3))) unsigned int*)l, 16, 0, 0);
}

// ---------------- K0: conversions ----------------
__global__ void k_cast_x(const float* __restrict__ x, short* __restrict__ xb) {
    int i = blockIdx.x * blockDim.x + threadIdx.x;
    f32x4 v = reinterpret_cast<const f32x4*>(x)[i];
    s16x4 o;
    o[0] = f2bf(v[0]); o[1] = f2bf(v[1]); o[2] = f2bf(v[2]); o[3] = f2bf(v[3]);
    reinterpret_cast<s16x4*>(xb)[i] = o;
}

__global__ void k_conv_wqkv(const float* __restrict__ Wq, const float* __restrict__ Wk,
                            const float* __restrict__ Wv, short* __restrict__ WT) {
    int idx = blockIdx.x * blockDim.x + threadIdx.x;
    int n = idx >> 10, d = idx & 1023;
    const float* src = Wq; int nn = n;
    if (n >= 2048)      { src = Wv; nn = n - 2048; }
    else if (n >= 1024) { src = Wk; nn = n - 1024; }
    int h = nn >> 6, kk = nn & 63;
    WT[idx] = f2bf(src[(h * DMODEL + d) * DK + kk]);
}

__global__ void k_conv_wfc(const float* __restrict__ Wfc, short* __restrict__ WfcT) {
    int idx = blockIdx.x * blockDim.x + threadIdx.x;
    int n = idx >> 10, c = idx & 1023;
    WfcT[idx] = f2bf(Wfc[c * 1024 + n]);
}

// ---------------- GEMM: C[M,N] = A[M,1024] * BT[N,1024]^T ----------------
template<int MODE>
__global__ __launch_bounds__(256) void k_gemm(const short* __restrict__ A,
                                              const short* __restrict__ BT,
                                              const float* __restrict__ bq,
                                              const float* __restrict__ bk,
                                              const float* __restrict__ bv,
                                              const float* __restrict__ bfc,
                                              short* __restrict__ Qb,
                                              short* __restrict__ Kb,
                                              short* __restrict__ Vb,
                                              float* __restrict__ Y) {
    __shared__ short sA[128][32];
    __shared__ short sB[128][32];
    const int gm0 = blockIdx.y * 128, gn0 = blockIdx.x * 128;
    const int t = threadIdx.x;
    const int lane = t & 63, w = t >> 6;
    const int wm = w >> 1, wn = w & 1;
    const int lr = lane & 15, lg = lane >> 4;

    f32x4 acc[4][4] = {};

    const int r = t >> 1, hh = (t & 1) * 16;
    const short* pa = A  + (size_t)(gm0 + r) * 1024 + hh;
    const short* pb = BT + (size_t)(gn0 + r) * 1024 + hh;

    for (int k0 = 0; k0 < 1024; k0 += 32) {
        *reinterpret_cast<s16x8*>(&sA[r][hh])     = *reinterpret_cast<const s16x8*>(pa + k0);
        *reinterpret_cast<s16x8*>(&sA[r][hh + 8]) = *reinterpret_cast<const s16x8*>(pa + k0 + 8);
        *reinterpret_cast<s16x8*>(&sB[r][hh])     = *reinterpret_cast<const s16x8*>(pb + k0);
        *reinterpret_cast<s16x8*>(&sB[r][hh + 8]) = *reinterpret_cast<const s16x8*>(pb + k0 + 8);
        __syncthreads();
        s16x8 aF[4], bF[4];
        #pragma unroll
        for (int i = 0; i < 4; i++) aF[i] = *reinterpret_cast<const s16x8*>(&sA[wm * 64 + i * 16 + lr][lg * 8]);
        #pragma unroll
        for (int i = 0; i < 4; i++) bF[i] = *reinterpret_cast<const s16x8*>(&sB[wn * 64 + i * 16 + lr][lg * 8]);
        #pragma unroll
        for (int i = 0; i < 4; i++)
            #pragma unroll
            for (int j = 0; j < 4; j++)
                acc[i][j] = __builtin_amdgcn_mfma_f32_16x16x32_bf16(aF[i], bF[j], acc[i][j], 0, 0, 0);
        __syncthreads();
    }

    #pragma unroll
    for (int i = 0; i < 4; i++) {
        #pragma unroll
        for (int j = 0; j < 4; j++) {
            #pragma unroll
            for (int rg = 0; rg < 4; rg++) {
                int m = gm0 + wm * 64 + i * 16 + lg * 4 + rg;
                int n = gn0 + wn * 64 + j * 16 + lr;
                float val = acc[i][j][rg];
                if (MODE == 0) {
                    int b = m >> 11, s = m & 2047;
                    if (n < 1024) {
                        int h = n >> 6, kk = n & 63;
                        val = (val + bq[n]) * 0.18033688011112042f;  // (1/8)*log2(e)
                        Qb[((size_t)(b * NH + h) * SS + s) * DK + kk] = f2bf(val);
                    } else if (n < 2048) {
                        int n2 = n - 1024; int h = n2 >> 6, kk = n2 & 63;
                        Kb[((size_t)(b * NH + h) * SS + s) * DK + kk] = f2bf(val + bk[n2]);
                    } else {
                        int n2 = n - 2048; int h = n2 >> 6, kk = n2 & 63;
                        Vb[((size_t)(b * NH + h) * SS + s) * DK + kk] = f2bf(val + bv[n2]);
                    }
                } else {
                    Y[(size_t)m * 1024 + n] = val + bfc[n];
                }
            }
        }
    }
}

// ---------------- V transpose + PV-fragment permute ----------------
// VT[bh][vdim][key-permuted]: within each 32-key block, granule lg holds
// keys {lg*4..lg*4+3, 16+lg*4..16+lg*4+3}  (matches PV A-fragment b128 read)
__global__ __launch_bounds__(256) void k_transpose_v(const short* __restrict__ Vb,
                                                     short* __restrict__ VT) {
    __shared__ short tile[64][65];
    const int bh = blockIdx.y, s0 = blockIdx.x * 64;
    const short* src = Vb + ((size_t)bh * SS + s0) * 64;
    short* dst = VT + (size_t)bh * 64 * SS;
    const int t = threadIdx.x;
    {
        int r = t >> 2, c0 = (t & 3) * 16;
        s16x8 v0 = *reinterpret_cast<const s16x8*>(&src[r * 64 + c0]);
        s16x8 v1 = *reinterpret_cast<const s16x8*>(&src[r * 64 + c0 + 8]);
        #pragma unroll
        for (int i = 0; i < 8; i++) { tile[r][c0 + i] = v0[i]; tile[r][c0 + 8 + i] = v1[i]; }
    }
    __syncthreads();
    {
        int vv = t >> 2, so = (t & 3) * 16;
        int b32 = so >> 5, half = (so >> 4) & 1;
        short* drow = dst + (size_t)vv * SS + s0 + b32 * 32 + half * 4;
        #pragma unroll
        for (int lgp = 0; lgp < 4; lgp++) {
            s16x4 c;
            #pragma unroll
            for (int i = 0; i < 4; i++) c[i] = tile[b32 * 32 + half * 16 + lgp * 4 + i][vv];
            *reinterpret_cast<s16x4*>(drow + lgp * 8) = c;
        }
    }
}

// ---------------- Flash attention: LDS double-buffered, 32 q/wave ----------------
__global__ __launch_bounds__(256) void k_attn2(const short* __restrict__ Qb,
                                               const short* __restrict__ Kb,
                                               const short* __restrict__ VT2,
                                               short* __restrict__ cat) {
    __shared__ char smem[2][16384];      // per buf: [0,8K) K tile 64x128B, [8K,16K) V tile 64x128B
    const int qt = blockIdx.x, bh = blockIdx.y;
    const int b = bh >> 4, h = bh & 15;
    const int t = threadIdx.x, lane = t & 63, w = t >> 6;
    const int lr = lane & 15, lg = lane >> 4;

    // Q fragments: q = qt*128 + w*32 + f*16 + lr
    const short* Qbase = Qb + ((size_t)bh * SS + qt * 128 + w * 32) * DK;
    s16x8 qF[2][2];
    #pragma unroll
    for (int f = 0; f < 2; f++) {
        qF[f][0] = *(const s16x8*)(Qbase + (f * 16 + lr) * DK + lg * 8);
        qF[f][1] = *(const s16x8*)(Qbase + (f * 16 + lr) * DK + 32 + lg * 8);
    }

    // staging: wave w stages rows [16w,16w+16) of both K and V tiles.
    // LDS dest linear; SOURCE granule pre-swizzled: src_g = lds_g ^ (row&7)
    const char* Kbase = (const char*)(Kb + (size_t)bh * SS * DK);
    const char* Vbase = (const char*)(VT2 + (size_t)bh * DK * SS);
    const int rk0 = w * 16 + (lane >> 3), rk1 = rk0 + 8;
    const int gl = lane & 7;
    const char* pK0 = Kbase + rk0 * 128 + ((gl ^ (rk0 & 7)) << 4);
    const char* pK1 = Kbase + rk1 * 128 + ((gl ^ (rk1 & 7)) << 4);
    const char* pV0 = Vbase + rk0 * (SS * 2) + ((gl ^ (rk0 & 7)) << 4);
    const char* pV1 = Vbase + rk1 * (SS * 2) + ((gl ^ (rk1 & 7)) << 4);

    // read-side granule byte offsets (rows used in frags have row&7 == lr&7)
    const int x7 = lr & 7;
    const int gx0 = (lg ^ x7) << 4;
    const int gx1 = ((4 + lg) ^ x7) << 4;

    f32x4 acc[2][4] = {};
    float mrun[2] = {-1e30f, -1e30f}, ssum[2] = {0.f, 0.f};

    {   // prologue: stage tile 0 into buf 0
        char* d = smem[0];
        gll16(pK0, d + w * 2048);
        gll16(pK1, d + w * 2048 + 1024);
        gll16(pV0, d + 8192 + w * 2048);
        gll16(pV1, d + 8192 + w * 2048 + 1024);
    }
    __syncthreads();

    int cur = 0;
    for (int kt = 0; kt < SS; kt += 64) {
        if (kt + 64 < SS) {     // stage next tile into other buffer
            char* d = smem[cur ^ 1];
            const int oK = (kt + 64) * 128, oV = (kt + 64) * 2;
            gll16(pK0 + oK, d + w * 2048);
            gll16(pK1 + oK, d + w * 2048 + 1024);
            gll16(pV0 + oV, d + 8192 + w * 2048);
            gll16(pV1 + oV, d + 8192 + w * 2048 + 1024);
        }
        const char* bs = smem[cur];

        s16x8 kA[4][2];
        #pragma unroll
        for (int kg = 0; kg < 4; kg++) {
            const char* rp = bs + (kg * 16 + lr) * 128;
            kA[kg][0] = *(const s16x8*)(rp + gx0);
            kA[kg][1] = *(const s16x8*)(rp + gx1);
        }
        f32x4 st[2][4];
        __builtin_amdgcn_s_setprio(1);
        #pragma unroll
        for (int f = 0; f < 2; f++)
            #pragma unroll
            for (int kg = 0; kg < 4; kg++) {
                f32x4 z = {};
                z = __builtin_amdgcn_mfma_f32_16x16x32_bf16(kA[kg][0], qF[f][0], z, 0, 0, 0);
                st[f][kg] = __builtin_amdgcn_mfma_f32_16x16x32_bf16(kA[kg][1], qF[f][1], z, 0, 0, 0);
            }
        __builtin_amdgcn_s_setprio(0);

        s16x8 pb[2][2];
        #pragma unroll
        for (int f = 0; f < 2; f++) {
            float tmax = fmaxf(fmaxf(fmaxf(fmaxf(st[f][0][0], st[f][0][1]), fmaxf(st[f][0][2], st[f][0][3])),
                                     fmaxf(fmaxf(st[f][1][0], st[f][1][1]), fmaxf(st[f][1][2], st[f][1][3]))),
                               fmaxf(fmaxf(fmaxf(st[f][2][0], st[f][2][1]), fmaxf(st[f][2][2], st[f][2][3])),
                                     fmaxf(fmaxf(st[f][3][0], st[f][3][1]), fmaxf(st[f][3][2], st[f][3][3]))));
            tmax = fmaxf(tmax, __shfl_xor(tmax, 16));
            tmax = fmaxf(tmax, __shfl_xor(tmax, 32));
            if (!__all(tmax <= mrun[f] + 8.0f)) {        // defer-max (T13)
                float mnew = fmaxf(mrun[f], tmax);
                float alpha = exp2f(mrun[f] - mnew);
                mrun[f] = mnew;
                ssum[f] *= alpha;
                #pragma unroll
                for (int vt = 0; vt < 4; vt++)
                    #pragma unroll
                    for (int rg = 0; rg < 4; rg++) acc[f][vt][rg] *= alpha;
            }
            float p[4][4]; float tsum = 0.f;
            #pragma unroll
            for (int kg = 0; kg < 4; kg++)
                #pragma unroll
                for (int rg = 0; rg < 4; rg++) {
                    p[kg][rg] = exp2f(st[f][kg][rg] - mrun[f]);
                    tsum += p[kg][rg];
                }
            tsum += __shfl_xor(tsum, 16);
            tsum += __shfl_xor(tsum, 32);
            ssum[f] += tsum;
            #pragma unroll
            for (int ks = 0; ks < 2; ks++) {
                s16x8 v;
                #pragma unroll
                for (int j = 0; j < 4; j++) {
                    v[j]     = f2bf_fast(p[2 * ks][j]);
                    v[4 + j] = f2bf_fast(p[2 * ks + 1][j]);
                }
                pb[f][ks] = v;
            }
        }

        __builtin_amdgcn_s_setprio(1);
        #pragma unroll
        for (int vt = 0; vt < 4; vt++) {
            const char* rp = bs + 8192 + (vt * 16 + lr) * 128;
            s16x8 vA0 = *(const s16x8*)(rp + gx0);
            s16x8 vA1 = *(const s16x8*)(rp + gx1);
            #pragma unroll
            for (int f = 0; f < 2; f++) {
                acc[f][vt] = __builtin_amdgcn_mfma_f32_16x16x32_bf16(vA0, pb[f][0], acc[f][vt], 0, 0, 0);
                acc[f][vt] = __builtin_amdgcn_mfma_f32_16x16x32_bf16(vA1, pb[f][1], acc[f][vt], 0, 0, 0);
            }
        }
        __builtin_amdgcn_s_setprio(0);
        __syncthreads();
        cur ^= 1;
    }

    // epilogue: stage through LDS for coalesced cat write
    char* ods = smem[0] + w * 4096;          // 32 rows x 128B per wave
    float inv[2] = {1.0f / ssum[0], 1.0f / ssum[1]};
    #pragma unroll
    for (int f = 0; f < 2; f++)
        #pragma unroll
        for (int vt = 0; vt < 4; vt++)
            #pragma unroll
            for (int rg = 0; rg < 4; rg++)
                *(short*)(ods + (f * 16 + lr) * 128 + (vt * 16 + lg * 4 + rg) * 2) =
                    f2bf(acc[f][vt][rg] * inv[f]);
    __syncthreads();
    {
        int r = lane >> 1, hb = lane & 1;
        const char* srow = smem[0] + w * 4096 + r * 128 + hb * 64;
        int token = b * SS + qt * 128 + w * 32 + r;
        char* dst = (char*)(cat + (size_t)token * 1024 + h * 64 + hb * 32);
        #pragma unroll
        for (int i = 0; i < 4; i++)
            *(s16x8*)(dst + i * 16) = *(const s16x8*)(srow + i * 16);
    }
}

// ---------------- LayerNorm ----------------
__global__ __launch_bounds__(256) void k_ln(const float* __restrict__ Y,
                                            const float* __restrict__ gamma,
                                            const float* __restrict__ beta,
                                            float* __restrict__ out) {
    const int row = blockIdx.x;
    const int t = threadIdx.x;
    const float* y = Y + (size_t)row * 1024;
    f32x4 v = reinterpret_cast<const f32x4*>(y)[t];
    float s = v[0] + v[1] + v[2] + v[3];
    float s2 = v[0] * v[0] + v[1] * v[1] + v[2] * v[2] + v[3] * v[3];
    #pragma unroll
    for (int off = 32; off; off >>= 1) {
        s += __shfl_xor(s, off);
        s2 += __shfl_xor(s2, off);
    }
    __shared__ float red[8];
    int w = t >> 6, lane = t & 63;
    if (lane == 0) { red[w] = s; red[4 + w] = s2; }
    __syncthreads();
    float S = red[0] + red[1] + red[2] + red[3];
    float S2 = red[4] + red[5] + red[6] + red[7];
    float mu = S * (1.f / 1024.f);
    float var = S2 * (1.f / 1024.f) - mu * mu;
    float rs = rsqrtf(var + LN_EPS);
    f32x4 g = reinterpret_cast<const f32x4*>(gamma)[t];
    f32x4 be = reinterpret_cast<const f32x4*>(beta)[t];
    f32x4 o;
    #pragma unroll
    for (int i = 0; i < 4; i++) o[i] = (v[i] - mu) * rs * g[i] + be[i];
    reinterpret_cast<f32x4*>(out + (size_t)row * 1024)[t] = o;
}

// ---------------- launch ----------------
extern "C" void kernel_launch(void* const* d_in, const int* in_sizes, int n_in,
                              void* d_out, int out_size, void* d_ws, size_t ws_size,
                              hipStream_t stream) {
    const float* x    = (const float*)d_in[0];
    const float* Wq   = (const float*)d_in[1];
    const float* bq   = (const float*)d_in[2];
    const float* Wk   = (const float*)d_in[3];
    const float* bk   = (const float*)d_in[4];
    const float* Wv   = (const float*)d_in[5];
    const float* bv   = (const float*)d_in[6];
    const float* Wfc  = (const float*)d_in[7];
    const float* bfc  = (const float*)d_in[8];
    const float* gamma= (const float*)d_in[9];
    const float* beta = (const float*)d_in[10];
    float* out = (float*)d_out;

    char* p = (char*)d_ws;
    short* xb   = (short*)p; p += (size_t)NTOK * 1024 * 2;
    short* WT   = (short*)p; p += (size_t)3072 * 1024 * 2;
    short* WfcT = (short*)p; p += (size_t)1024 * 1024 * 2;
    short* Qb   = (short*)p; p += (size_t)64 * SS * 64 * 2;
    short* Kb   = (short*)p; p += (size_t)64 * SS * 64 * 2;
    short* Vb   = (short*)p; p += (size_t)64 * SS * 64 * 2;
    short* VTb  = (short*)p; p += (size_t)64 * 64 * SS * 2;
    short* cat  = (short*)p; p += (size_t)NTOK * 1024 * 2;
    float* Y    = (float*)Qb;  // aliases Qb+Kb (dead after k_attn2)

    k_cast_x   <<<NTOK * 1024 / 4 / 256, 256, 0, stream>>>(x, xb);
    k_conv_wqkv<<<3072 * 1024 / 256, 256, 0, stream>>>(Wq, Wk, Wv, WT);
    k_conv_wfc <<<1024 * 1024 / 256, 256, 0, stream>>>(Wfc, WfcT);
    k_gemm<0>  <<<dim3(24, 64), 256, 0, stream>>>(xb, WT, bq, bk, bv, nullptr, Qb, Kb, Vb, nullptr);
    k_transpose_v<<<dim3(SS / 64, 64), 256, 0, stream>>>(Vb, VTb);
    k_attn2    <<<dim3(SS / 128, 64), 256, 0, stream>>>(Qb, Kb, VTb, cat);
    k_gemm<1>  <<<dim3(8, 64), 256, 0, stream>>>(cat, WfcT, nullptr, nullptr, nullptr, bfc, nullptr, nullptr, nullptr, Y);
    k_ln       <<<NTOK, 256, 0, stream>>>(Y, gamma, beta, out);
}

// Round 3
// 315.345 us; speedup vs baseline: 2.7503x; 1.0885x over previous
//
#include <hip/hip_runtime.h>

#define NH 16
#define DMODEL 1024
#define DK 64
#define DV 64
#define BB 4
#define SS 2048
#define NTOK (BB*SS)
#define LN_EPS 1e-5f

typedef __attribute__((ext_vector_type(4))) float f32x4;
typedef __attribute__((ext_vector_type(8))) short s16x8;
typedef __attribute__((ext_vector_type(4))) short s16x4;

__device__ __forceinline__ short f2bf(float f) {
    union { float f; unsigned u; } a; a.f = f;
    unsigned r = a.u + 0x7FFFu + ((a.u >> 16) & 1u);
    return (short)(r >> 16);
}
// pack two floats -> (bf16(a)<<16)|bf16(b), round-half-up
__device__ __forceinline__ unsigned pk2(float a, float b) {
    union { float f; unsigned u; } x, y; x.f = a; y.f = b;
    return __builtin_amdgcn_perm(x.u + 0x8000u, y.u + 0x8000u, 0x07060302u);
}
__device__ __forceinline__ void gll16(const void* g, void* l) {
    __builtin_amdgcn_global_load_lds(
        (const __attribute__((address_space(1))) unsigned int*)g,
        (__attribute__((address_space(3))) unsigned int*)l, 16, 0, 0);
}

// ---------------- K0: cast x ----------------
__global__ void k_cast_x(const float* __restrict__ x, short* __restrict__ xb) {
    int i = blockIdx.x * blockDim.x + threadIdx.x;
    f32x4 v = reinterpret_cast<const f32x4*>(x)[i];
    s16x4 o;
    o[0] = f2bf(v[0]); o[1] = f2bf(v[1]); o[2] = f2bf(v[2]); o[3] = f2bf(v[3]);
    reinterpret_cast<s16x4*>(xb)[i] = o;
}

// ---------------- tiled transpose-cast: Wq/Wk/Wv [h][d][kk] -> WT[mat*1024+h*64+kk][d]
__global__ __launch_bounds__(256) void k_conv_wqkv_t(const float* __restrict__ Wq,
                                                     const float* __restrict__ Wk,
                                                     const float* __restrict__ Wv,
                                                     short* __restrict__ WT) {
    __shared__ float tile[64][17];
    const int mh = blockIdx.y;                      // 0..47
    const int mat = mh >> 4, h = mh & 15;
    const int dt = blockIdx.x >> 2, kt = blockIdx.x & 3;
    const float* src = (mat == 0 ? Wq : (mat == 1 ? Wk : Wv));
    const int t = threadIdx.x;
    #pragma unroll
    for (int p = 0; p < 4; p++) {
        int d = p * 16 + (t >> 4), kk = t & 15;
        tile[d][kk] = src[((size_t)h * 1024 + dt * 64 + d) * 64 + kt * 16 + kk];
    }
    __syncthreads();
    #pragma unroll
    for (int p = 0; p < 4; p++) {
        int kk = p * 4 + (t >> 6), d = t & 63;
        WT[((size_t)mat * 1024 + h * 64 + kt * 16 + kk) * 1024 + dt * 64 + d] = f2bf(tile[d][kk]);
    }
}

// WfcT[n][c] = Wfc[c][n], tiled
__global__ __launch_bounds__(256) void k_conv_wfc_t(const float* __restrict__ Wfc,
                                                    short* __restrict__ WfcT) {
    __shared__ float tile[64][17];
    const int ct = blockIdx.x >> 6, nt = blockIdx.x & 63;
    const int t = threadIdx.x;
    #pragma unroll
    for (int p = 0; p < 4; p++) {
        int c = p * 16 + (t >> 4), n = t & 15;
        tile[c][n] = Wfc[((size_t)ct * 64 + c) * 1024 + nt * 16 + n];
    }
    __syncthreads();
    #pragma unroll
    for (int p = 0; p < 4; p++) {
        int n = p * 4 + (t >> 6), c = t & 63;
        WfcT[((size_t)nt * 16 + n) * 1024 + ct * 64 + c] = f2bf(tile[c][n]);
    }
}

// ---------------- GEMM (m97 structure): C[M,N] = A[M,1024] * BT[N,1024]^T ----------------
// global_load_lds width-16 staging, pre-swizzled source granules (g ^ (row&3)),
// linear LDS dest, swizzle-matched ds_read_b128 fragments.
template<int MODE>
__global__ __launch_bounds__(256) void k_gemm2(const short* __restrict__ A,
                                               const short* __restrict__ BT,
                                               const float* __restrict__ bq,
                                               const float* __restrict__ bk,
                                               const float* __restrict__ bv,
                                               const float* __restrict__ bfc,
                                               short* __restrict__ Qb,
                                               short* __restrict__ Kb,
                                               short* __restrict__ Vb,
                                               float* __restrict__ Y) {
    __shared__ short sA[128][32];
    __shared__ short sB[128][32];
    const int gm0 = blockIdx.y * 128, gn0 = blockIdx.x * 128;
    const int t = threadIdx.x, lane = t & 63, w = t >> 6;
    const int wm = w >> 1, wn = w & 1;
    const int lr = lane & 15, lg = lane >> 4;

    f32x4 acc[4][4] = {};

    // staging: wave w covers rows [w*32, w*32+32) of both tiles, two 1KB calls each
    const int r0 = w * 32 + (lane >> 2);
    const int g0 = lane & 3;
    const int sgx = (g0 ^ (r0 & 3)) << 3;           // swizzled source granule (shorts)
    const short* pa0 = A  + (size_t)(gm0 + r0) * 1024 + sgx;
    const short* pa1 = pa0 + 16 * 1024;             // (r0+16)&3 == r0&3
    const short* pb0 = BT + (size_t)(gn0 + r0) * 1024 + sgx;
    const short* pb1 = pb0 + 16 * 1024;
    char* dA0 = (char*)sA + w * 2048;
    char* dA1 = dA0 + 1024;
    char* dB0 = (char*)sB + w * 2048;
    char* dB1 = dB0 + 1024;

    const int xg = (lg ^ (lr & 3)) << 4;            // read-side swizzled granule (bytes)

    for (int k0 = 0; k0 < 1024; k0 += 32) {
        gll16(pa0 + k0, dA0);
        gll16(pa1 + k0, dA1);
        gll16(pb0 + k0, dB0);
        gll16(pb1 + k0, dB1);
        __syncthreads();
        s16x8 aF[4], bF[4];
        #pragma unroll
        for (int i = 0; i < 4; i++)
            aF[i] = *(const s16x8*)((char*)sA + (wm * 64 + i * 16 + lr) * 64 + xg);
        #pragma unroll
        for (int i = 0; i < 4; i++)
            bF[i] = *(const s16x8*)((char*)sB + (wn * 64 + i * 16 + lr) * 64 + xg);
        __builtin_amdgcn_s_setprio(1);
        #pragma unroll
        for (int i = 0; i < 4; i++)
            #pragma unroll
            for (int j = 0; j < 4; j++)
                acc[i][j] = __builtin_amdgcn_mfma_f32_16x16x32_bf16(aF[i], bF[j], acc[i][j], 0, 0, 0);
        __builtin_amdgcn_s_setprio(0);
        __syncthreads();
    }

    #pragma unroll
    for (int i = 0; i < 4; i++) {
        #pragma unroll
        for (int j = 0; j < 4; j++) {
            #pragma unroll
            for (int rg = 0; rg < 4; rg++) {
                int m = gm0 + wm * 64 + i * 16 + lg * 4 + rg;
                int n = gn0 + wn * 64 + j * 16 + lr;
                float val = acc[i][j][rg];
                if (MODE == 0) {
                    int b = m >> 11, s = m & 2047;
                    if (n < 1024) {
                        int h = n >> 6, kk = n & 63;
                        val = (val + bq[n]) * 0.18033688011112042f;  // (1/8)*log2(e)
                        Qb[((size_t)(b * NH + h) * SS + s) * DK + kk] = f2bf(val);
                    } else if (n < 2048) {
                        int n2 = n - 1024; int h = n2 >> 6, kk = n2 & 63;
                        Kb[((size_t)(b * NH + h) * SS + s) * DK + kk] = f2bf(val + bk[n2]);
                    } else {
                        int n2 = n - 2048; int h = n2 >> 6, kk = n2 & 63;
                        Vb[((size_t)(b * NH + h) * SS + s) * DK + kk] = f2bf(val + bv[n2]);
                    }
                } else {
                    Y[(size_t)m * 1024 + n] = val + bfc[n];
                }
            }
        }
    }
}

// ---------------- V transpose + PV-fragment permute ----------------
__global__ __launch_bounds__(256) void k_transpose_v(const short* __restrict__ Vb,
                                                     short* __restrict__ VT) {
    __shared__ short tile[64][65];
    const int bh = blockIdx.y, s0 = blockIdx.x * 64;
    const short* src = Vb + ((size_t)bh * SS + s0) * 64;
    short* dst = VT + (size_t)bh * 64 * SS;
    const int t = threadIdx.x;
    {
        int r = t >> 2, c0 = (t & 3) * 16;
        s16x8 v0 = *reinterpret_cast<const s16x8*>(&src[r * 64 + c0]);
        s16x8 v1 = *reinterpret_cast<const s16x8*>(&src[r * 64 + c0 + 8]);
        #pragma unroll
        for (int i = 0; i < 8; i++) { tile[r][c0 + i] = v0[i]; tile[r][c0 + 8 + i] = v1[i]; }
    }
    __syncthreads();
    {
        int vv = t >> 2, so = (t & 3) * 16;
        int b32 = so >> 5, half = (so >> 4) & 1;
        short* drow = dst + (size_t)vv * SS + s0 + b32 * 32 + half * 4;
        #pragma unroll
        for (int lgp = 0; lgp < 4; lgp++) {
            s16x4 c;
            #pragma unroll
            for (int i = 0; i < 4; i++) c[i] = tile[b32 * 32 + half * 16 + lgp * 4 + i][vv];
            *reinterpret_cast<s16x4*>(drow + lgp * 8) = c;
        }
    }
}

// ---------------- Flash attention ----------------
__global__ __launch_bounds__(256) void k_attn2(const short* __restrict__ Qb,
                                               const short* __restrict__ Kb,
                                               const short* __restrict__ VT2,
                                               short* __restrict__ cat) {
    __shared__ char smem[2][16384];
    // XCD-bijective swizzle: each XCD gets 8 consecutive bh (K+V = 4MB = L2)
    const int fid = blockIdx.x + blockIdx.y * gridDim.x;      // 0..1023
    const int swz = ((fid & 7) << 7) | (fid >> 3);
    const int qt = swz & 15, bh = swz >> 4;
    const int b = bh >> 4, h = bh & 15;
    const int t = threadIdx.x, lane = t & 63, w = t >> 6;
    const int lr = lane & 15, lg = lane >> 4;

    const short* Qbase = Qb + ((size_t)bh * SS + qt * 128 + w * 32) * DK;
    s16x8 qF[2][2];
    #pragma unroll
    for (int f = 0; f < 2; f++) {
        qF[f][0] = *(const s16x8*)(Qbase + (f * 16 + lr) * DK + lg * 8);
        qF[f][1] = *(const s16x8*)(Qbase + (f * 16 + lr) * DK + 32 + lg * 8);
    }
    s16x8 onesF;
    #pragma unroll
    for (int i = 0; i < 8; i++) onesF[i] = (short)0x3F80;     // bf16 1.0

    const char* Kbase = (const char*)(Kb + (size_t)bh * SS * DK);
    const char* Vbase = (const char*)(VT2 + (size_t)bh * DK * SS);
    const int rk0 = w * 16 + (lane >> 3), rk1 = rk0 + 8;
    const int gl = lane & 7;
    const char* pK0 = Kbase + rk0 * 128 + ((gl ^ (rk0 & 7)) << 4);
    const char* pK1 = Kbase + rk1 * 128 + ((gl ^ (rk1 & 7)) << 4);
    const char* pV0 = Vbase + rk0 * (SS * 2) + ((gl ^ (rk0 & 7)) << 4);
    const char* pV1 = Vbase + rk1 * (SS * 2) + ((gl ^ (rk1 & 7)) << 4);

    const int x7 = lr & 7;
    const int gx0 = (lg ^ x7) << 4;
    const int gx1 = ((4 + lg) ^ x7) << 4;

    f32x4 acc[2][4] = {};
    f32x4 accs[2] = {};                  // row-sum accumulator (ones-column MFMA)
    float mrun[2] = {-1e30f, -1e30f};

    {
        char* d = smem[0];
        gll16(pK0, d + w * 2048);
        gll16(pK1, d + w * 2048 + 1024);
        gll16(pV0, d + 8192 + w * 2048);
        gll16(pV1, d + 8192 + w * 2048 + 1024);
    }
    __syncthreads();

    int cur = 0;
    for (int kt = 0; kt < SS; kt += 64) {
        if (kt + 64 < SS) {
            char* d = smem[cur ^ 1];
            const int oK = (kt + 64) * 128, oV = (kt + 64) * 2;
            gll16(pK0 + oK, d + w * 2048);
            gll16(pK1 + oK, d + w * 2048 + 1024);
            gll16(pV0 + oV, d + 8192 + w * 2048);
            gll16(pV1 + oV, d + 8192 + w * 2048 + 1024);
        }
        const char* bs = smem[cur];

        s16x8 kA[4][2];
        #pragma unroll
        for (int kg = 0; kg < 4; kg++) {
            const char* rp = bs + (kg * 16 + lr) * 128;
            kA[kg][0] = *(const s16x8*)(rp + gx0);
            kA[kg][1] = *(const s16x8*)(rp + gx1);
        }
        f32x4 st[2][4];
        __builtin_amdgcn_s_setprio(1);
        #pragma unroll
        for (int f = 0; f < 2; f++)
            #pragma unroll
            for (int kg = 0; kg < 4; kg++) {
                f32x4 z = {};
                z = __builtin_amdgcn_mfma_f32_16x16x32_bf16(kA[kg][0], qF[f][0], z, 0, 0, 0);
                st[f][kg] = __builtin_amdgcn_mfma_f32_16x16x32_bf16(kA[kg][1], qF[f][1], z, 0, 0, 0);
            }
        __builtin_amdgcn_s_setprio(0);

        s16x8 pb[2][2];
        #pragma unroll
        for (int f = 0; f < 2; f++) {
            float tmax = fmaxf(fmaxf(fmaxf(fmaxf(st[f][0][0], st[f][0][1]), fmaxf(st[f][0][2], st[f][0][3])),
                                     fmaxf(fmaxf(st[f][1][0], st[f][1][1]), fmaxf(st[f][1][2], st[f][1][3]))),
                               fmaxf(fmaxf(fmaxf(st[f][2][0], st[f][2][1]), fmaxf(st[f][2][2], st[f][2][3])),
                                     fmaxf(fmaxf(st[f][3][0], st[f][3][1]), fmaxf(st[f][3][2], st[f][3][3]))));
            tmax = fmaxf(tmax, __shfl_xor(tmax, 16));
            tmax = fmaxf(tmax, __shfl_xor(tmax, 32));
            if (!__all(tmax <= mrun[f] + 8.0f)) {        // defer-max (T13)
                float mnew = fmaxf(mrun[f], tmax);
                float alpha = exp2f(mrun[f] - mnew);
                mrun[f] = mnew;
                #pragma unroll
                for (int rg = 0; rg < 4; rg++) accs[f][rg] *= alpha;
                #pragma unroll
                for (int vt = 0; vt < 4; vt++)
                    #pragma unroll
                    for (int rg = 0; rg < 4; rg++) acc[f][vt][rg] *= alpha;
            }
            float p[4][4];
            #pragma unroll
            for (int kg = 0; kg < 4; kg++)
                #pragma unroll
                for (int rg = 0; rg < 4; rg++)
                    p[kg][rg] = exp2f(st[f][kg][rg] - mrun[f]);
            #pragma unroll
            for (int ks = 0; ks < 2; ks++) {
                union { s16x8 v; unsigned u[4]; } U;
                U.u[0] = pk2(p[2 * ks][1],     p[2 * ks][0]);
                U.u[1] = pk2(p[2 * ks][3],     p[2 * ks][2]);
                U.u[2] = pk2(p[2 * ks + 1][1], p[2 * ks + 1][0]);
                U.u[3] = pk2(p[2 * ks + 1][3], p[2 * ks + 1][2]);
                pb[f][ks] = U.v;
            }
        }

        __builtin_amdgcn_s_setprio(1);
        #pragma unroll
        for (int f = 0; f < 2; f++) {        // row-sum via ones-column
            accs[f] = __builtin_amdgcn_mfma_f32_16x16x32_bf16(onesF, pb[f][0], accs[f], 0, 0, 0);
            accs[f] = __builtin_amdgcn_mfma_f32_16x16x32_bf16(onesF, pb[f][1], accs[f], 0, 0, 0);
        }
        #pragma unroll
        for (int vt = 0; vt < 4; vt++) {
            const char* rp = bs + 8192 + (vt * 16 + lr) * 128;
            s16x8 vA0 = *(const s16x8*)(rp + gx0);
            s16x8 vA1 = *(const s16x8*)(rp + gx1);
            #pragma unroll
            for (int f = 0; f < 2; f++) {
                acc[f][vt] = __builtin_amdgcn_mfma_f32_16x16x32_bf16(vA0, pb[f][0], acc[f][vt], 0, 0, 0);
                acc[f][vt] = __builtin_amdgcn_mfma_f32_16x16x32_bf16(vA1, pb[f][1], acc[f][vt], 0, 0, 0);
            }
        }
        __builtin_amdgcn_s_setprio(0);
        __syncthreads();
        cur ^= 1;
    }

    char* ods = smem[0] + w * 4096;
    float inv[2] = {1.0f / accs[0][0], 1.0f / accs[1][0]};
    #pragma unroll
    for (int f = 0; f < 2; f++)
        #pragma unroll
        for (int vt = 0; vt < 4; vt++)
            #pragma unroll
            for (int rg = 0; rg < 4; rg++)
                *(short*)(ods + (f * 16 + lr) * 128 + (vt * 16 + lg * 4 + rg) * 2) =
                    f2bf(acc[f][vt][rg] * inv[f]);
    __syncthreads();
    {
        int r = lane >> 1, hb = lane & 1;
        const char* srow = smem[0] + w * 4096 + r * 128 + hb * 64;
        int token = b * SS + qt * 128 + w * 32 + r;
        char* dst = (char*)(cat + (size_t)token * 1024 + h * 64 + hb * 32);
        #pragma unroll
        for (int i = 0; i < 4; i++)
            *(s16x8*)(dst + i * 16) = *(const s16x8*)(srow + i * 16);
    }
}

// ---------------- LayerNorm ----------------
__global__ __launch_bounds__(256) void k_ln(const float* __restrict__ Y,
                                            const float* __restrict__ gamma,
                                            const float* __restrict__ beta,
                                            float* __restrict__ out) {
    const int row = blockIdx.x;
    const int t = threadIdx.x;
    const float* y = Y + (size_t)row * 1024;
    f32x4 v = reinterpret_cast<const f32x4*>(y)[t];
    float s = v[0] + v[1] + v[2] + v[3];
    float s2 = v[0] * v[0] + v[1] * v[1] + v[2] * v[2] + v[3] * v[3];
    #pragma unroll
    for (int off = 32; off; off >>= 1) {
        s += __shfl_xor(s, off);
        s2 += __shfl_xor(s2, off);
    }
    __shared__ float red[8];
    int w = t >> 6, lane = t & 63;
    if (lane == 0) { red[w] = s; red[4 + w] = s2; }
    __syncthreads();
    float S = red[0] + red[1] + red[2] + red[3];
    float S2 = red[4] + red[5] + red[6] + red[7];
    float mu = S * (1.f / 1024.f);
    float var = S2 * (1.f / 1024.f) - mu * mu;
    float rs = rsqrtf(var + LN_EPS);
    f32x4 g = reinterpret_cast<const f32x4*>(gamma)[t];
    f32x4 be = reinterpret_cast<const f32x4*>(beta)[t];
    f32x4 o;
    #pragma unroll
    for (int i = 0; i < 4; i++) o[i] = (v[i] - mu) * rs * g[i] + be[i];
    reinterpret_cast<f32x4*>(out + (size_t)row * 1024)[t] = o;
}

// ---------------- launch ----------------
extern "C" void kernel_launch(void* const* d_in, const int* in_sizes, int n_in,
                              void* d_out, int out_size, void* d_ws, size_t ws_size,
                              hipStream_t stream) {
    const float* x    = (const float*)d_in[0];
    const float* Wq   = (const float*)d_in[1];
    const float* bq   = (const float*)d_in[2];
    const float* Wk   = (const float*)d_in[3];
    const float* bk   = (const float*)d_in[4];
    const float* Wv   = (const float*)d_in[5];
    const float* bv   = (const float*)d_in[6];
    const float* Wfc  = (const float*)d_in[7];
    const float* bfc  = (const float*)d_in[8];
    const float* gamma= (const float*)d_in[9];
    const float* beta = (const float*)d_in[10];
    float* out = (float*)d_out;

    char* p = (char*)d_ws;
    short* xb   = (short*)p; p += (size_t)NTOK * 1024 * 2;
    short* WT   = (short*)p; p += (size_t)3072 * 1024 * 2;
    short* WfcT = (short*)p; p += (size_t)1024 * 1024 * 2;
    short* Qb   = (short*)p; p += (size_t)64 * SS * 64 * 2;
    short* Kb   = (short*)p; p += (size_t)64 * SS * 64 * 2;
    short* Vb   = (short*)p; p += (size_t)64 * SS * 64 * 2;
    short* VTb  = (short*)p; p += (size_t)64 * 64 * SS * 2;
    short* cat  = (short*)p; p += (size_t)NTOK * 1024 * 2;
    float* Y    = (float*)Qb;  // aliases Qb+Kb (dead after k_attn2)

    k_cast_x     <<<NTOK * 1024 / 4 / 256, 256, 0, stream>>>(x, xb);
    k_conv_wqkv_t<<<dim3(64, 48), 256, 0, stream>>>(Wq, Wk, Wv, WT);
    k_conv_wfc_t <<<1024, 256, 0, stream>>>(Wfc, WfcT);
    k_gemm2<0>   <<<dim3(24, 64), 256, 0, stream>>>(xb, WT, bq, bk, bv, nullptr, Qb, Kb, Vb, nullptr);
    k_transpose_v<<<dim3(SS / 64, 64), 256, 0, stream>>>(Vb, VTb);
    k_attn2      <<<dim3(SS / 128, 64), 256, 0, stream>>>(Qb, Kb, VTb, cat);
    k_gemm2<1>   <<<dim3(8, 64), 256, 0, stream>>>(cat, WfcT, nullptr, nullptr, nullptr, bfc, nullptr, nullptr, nullptr, Y);
    k_ln         <<<NTOK, 256, 0, stream>>>(Y, gamma, beta, out);
}

// Round 5
// 284.005 us; speedup vs baseline: 3.0538x; 1.1103x over previous
//
#include <hip/hip_runtime.h>

#define NH 16
#define DMODEL 1024
#define DK 64
#define DV 64
#define BB 4
#define SS 2048
#define NTOK (BB*SS)
#define LN_EPS 1e-5f

typedef __attribute__((ext_vector_type(4))) float f32x4;
typedef __attribute__((ext_vector_type(8))) short s16x8;
typedef __attribute__((ext_vector_type(4))) short s16x4;

__device__ __forceinline__ short f2bf(float f) {
    union { float f; unsigned u; } a; a.f = f;
    unsigned r = a.u + 0x7FFFu + ((a.u >> 16) & 1u);
    return (short)(r >> 16);
}
// pack two floats -> (bf16(a)<<16)|bf16(b), round-half-up
__device__ __forceinline__ unsigned pk2(float a, float b) {
    union { float f; unsigned u; } x, y; x.f = a; y.f = b;
    return __builtin_amdgcn_perm(x.u + 0x8000u, y.u + 0x8000u, 0x07060302u);
}
// bare v_exp_f32 (2^x): avoids __ocml_exp2_f32 libcall; FTZ on underflow is desired
__device__ __forceinline__ float fexp2(float x) { return __builtin_amdgcn_exp2f(x); }
__device__ __forceinline__ void gll16(const void* g, void* l) {
    __builtin_amdgcn_global_load_lds(
        (const __attribute__((address_space(1))) unsigned int*)g,
        (__attribute__((address_space(3))) unsigned int*)l, 16, 0, 0);
}

// ---------------- K0: cast x ----------------
__global__ void k_cast_x(const float* __restrict__ x, short* __restrict__ xb) {
    int i = blockIdx.x * blockDim.x + threadIdx.x;
    f32x4 v = reinterpret_cast<const f32x4*>(x)[i];
    s16x4 o;
    o[0] = f2bf(v[0]); o[1] = f2bf(v[1]); o[2] = f2bf(v[2]); o[3] = f2bf(v[3]);
    reinterpret_cast<s16x4*>(xb)[i] = o;
}

// ---------------- tiled transpose-cast: Wq/Wk/Wv [h][d][kk] -> WT[mat*1024+h*64+kk][d]
__global__ __launch_bounds__(256) void k_conv_wqkv_t(const float* __restrict__ Wq,
                                                     const float* __restrict__ Wk,
                                                     const float* __restrict__ Wv,
                                                     short* __restrict__ WT) {
    __shared__ float tile[64][17];
    const int mh = blockIdx.y;
    const int mat = mh >> 4, h = mh & 15;
    const int dt = blockIdx.x >> 2, kt = blockIdx.x & 3;
    const float* src = (mat == 0 ? Wq : (mat == 1 ? Wk : Wv));
    const int t = threadIdx.x;
    #pragma unroll
    for (int p = 0; p < 4; p++) {
        int d = p * 16 + (t >> 4), kk = t & 15;
        tile[d][kk] = src[((size_t)h * 1024 + dt * 64 + d) * 64 + kt * 16 + kk];
    }
    __syncthreads();
    #pragma unroll
    for (int p = 0; p < 4; p++) {
        int kk = p * 4 + (t >> 6), d = t & 63;
        WT[((size_t)mat * 1024 + h * 64 + kt * 16 + kk) * 1024 + dt * 64 + d] = f2bf(tile[d][kk]);
    }
}

__global__ __launch_bounds__(256) void k_conv_wfc_t(const float* __restrict__ Wfc,
                                                    short* __restrict__ WfcT) {
    __shared__ float tile[64][17];
    const int ct = blockIdx.x >> 6, nt = blockIdx.x & 63;
    const int t = threadIdx.x;
    #pragma unroll
    for (int p = 0; p < 4; p++) {
        int c = p * 16 + (t >> 4), n = t & 15;
        tile[c][n] = Wfc[((size_t)ct * 64 + c) * 1024 + nt * 16 + n];
    }
    __syncthreads();
    #pragma unroll
    for (int p = 0; p < 4; p++) {
        int n = p * 4 + (t >> 6), c = t & 63;
        WfcT[((size_t)nt * 16 + n) * 1024 + ct * 64 + c] = f2bf(tile[c][n]);
    }
}

// ---------------- GEMM (m97 structure, BK=32): C[M,N] = A[M,1024] * BT[N,1024]^T
template<int MODE>
__global__ __launch_bounds__(256) void k_gemm2(const short* __restrict__ A,
                                               const short* __restrict__ BT,
                                               const float* __restrict__ bq,
                                               const float* __restrict__ bk,
                                               const float* __restrict__ bv,
                                               const float* __restrict__ bfc,
                                               short* __restrict__ Qb,
                                               short* __restrict__ Kb,
                                               short* __restrict__ Vb,
                                               float* __restrict__ Y) {
    __shared__ short sA[128][32];
    __shared__ short sB[128][32];
    const int gm0 = blockIdx.y * 128, gn0 = blockIdx.x * 128;
    const int t = threadIdx.x, lane = t & 63, w = t >> 6;
    const int wm = w >> 1, wn = w & 1;
    const int lr = lane & 15, lg = lane >> 4;

    f32x4 acc[4][4] = {};

    // staging: wave w covers rows [w*32, w*32+32) of both tiles, two 1KB calls each
    const int r0 = w * 32 + (lane >> 2);
    const int g0 = lane & 3;
    const int sgx = (g0 ^ (r0 & 3)) << 3;           // swizzled source granule (shorts)
    const short* pa0 = A  + (size_t)(gm0 + r0) * 1024 + sgx;
    const short* pa1 = pa0 + 16 * 1024;             // (r0+16)&3 == r0&3
    const short* pb0 = BT + (size_t)(gn0 + r0) * 1024 + sgx;
    const short* pb1 = pb0 + 16 * 1024;
    char* dA0 = (char*)sA + w * 2048;
    char* dA1 = dA0 + 1024;
    char* dB0 = (char*)sB + w * 2048;
    char* dB1 = dB0 + 1024;

    const int xg = (lg ^ (lr & 3)) << 4;            // read-side swizzled granule (bytes)

    for (int k0 = 0; k0 < 1024; k0 += 32) {
        gll16(pa0 + k0, dA0);
        gll16(pa1 + k0, dA1);
        gll16(pb0 + k0, dB0);
        gll16(pb1 + k0, dB1);
        __syncthreads();
        s16x8 aF[4], bF[4];
        #pragma unroll
        for (int i = 0; i < 4; i++)
            aF[i] = *(const s16x8*)((char*)sA + (wm * 64 + i * 16 + lr) * 64 + xg);
        #pragma unroll
        for (int i = 0; i < 4; i++)
            bF[i] = *(const s16x8*)((char*)sB + (wn * 64 + i * 16 + lr) * 64 + xg);
        __builtin_amdgcn_s_setprio(1);
        #pragma unroll
        for (int i = 0; i < 4; i++)
            #pragma unroll
            for (int j = 0; j < 4; j++)
                acc[i][j] = __builtin_amdgcn_mfma_f32_16x16x32_bf16(aF[i], bF[j], acc[i][j], 0, 0, 0);
        __builtin_amdgcn_s_setprio(0);
        __syncthreads();
    }

    #pragma unroll
    for (int i = 0; i < 4; i++) {
        #pragma unroll
        for (int j = 0; j < 4; j++) {
            #pragma unroll
            for (int rg = 0; rg < 4; rg++) {
                int m = gm0 + wm * 64 + i * 16 + lg * 4 + rg;
                int n = gn0 + wn * 64 + j * 16 + lr;
                float val = acc[i][j][rg];
                if (MODE == 0) {
                    int b = m >> 11, s = m & 2047;
                    if (n < 1024) {
                        int h = n >> 6, kk = n & 63;
                        val = (val + bq[n]) * 0.18033688011112042f;  // (1/8)*log2(e)
                        Qb[((size_t)(b * NH + h) * SS + s) * DK + kk] = f2bf(val);
                    } else if (n < 2048) {
                        int n2 = n - 1024; int h = n2 >> 6, kk = n2 & 63;
                        Kb[((size_t)(b * NH + h) * SS + s) * DK + kk] = f2bf(val + bk[n2]);
                    } else {
                        int n2 = n - 2048; int h = n2 >> 6, kk = n2 & 63;
                        Vb[((size_t)(b * NH + h) * SS + s) * DK + kk] = f2bf(val + bv[n2]);
                    }
                } else {
                    Y[(size_t)m * 1024 + n] = val + bfc[n];
                }
            }
        }
    }
}

// ---------------- V transpose + PV-fragment permute ----------------
__global__ __launch_bounds__(256) void k_transpose_v(const short* __restrict__ Vb,
                                                     short* __restrict__ VT) {
    __shared__ short tile[64][65];
    const int bh = blockIdx.y, s0 = blockIdx.x * 64;
    const short* src = Vb + ((size_t)bh * SS + s0) * 64;
    short* dst = VT + (size_t)bh * 64 * SS;
    const int t = threadIdx.x;
    {
        int r = t >> 2, c0 = (t & 3) * 16;
        s16x8 v0 = *reinterpret_cast<const s16x8*>(&src[r * 64 + c0]);
        s16x8 v1 = *reinterpret_cast<const s16x8*>(&src[r * 64 + c0 + 8]);
        #pragma unroll
        for (int i = 0; i < 8; i++) { tile[r][c0 + i] = v0[i]; tile[r][c0 + 8 + i] = v1[i]; }
    }
    __syncthreads();
    {
        int vv = t >> 2, so = (t & 3) * 16;
        int b32 = so >> 5, half = (so >> 4) & 1;
        short* drow = dst + (size_t)vv * SS + s0 + b32 * 32 + half * 4;
        #pragma unroll
        for (int lgp = 0; lgp < 4; lgp++) {
            s16x4 c;
            #pragma unroll
            for (int i = 0; i < 4; i++) c[i] = tile[b32 * 32 + half * 16 + lgp * 4 + i][vv];
            *reinterpret_cast<s16x4*>(drow + lgp * 8) = c;
        }
    }
}

// ---------------- Flash attention ----------------
__global__ __launch_bounds__(256) void k_attn2(const short* __restrict__ Qb,
                                               const short* __restrict__ Kb,
                                               const short* __restrict__ VT2,
                                               short* __restrict__ cat) {
    __shared__ char smem[2][16384];
    // XCD-bijective swizzle: each XCD gets 8 consecutive bh (K+V = 4MB = L2)
    const int fid = blockIdx.x + blockIdx.y * gridDim.x;      // 0..1023
    const int swz = ((fid & 7) << 7) | (fid >> 3);
    const int qt = swz & 15, bh = swz >> 4;
    const int b = bh >> 4, h = bh & 15;
    const int t = threadIdx.x, lane = t & 63, w = t >> 6;
    const int lr = lane & 15, lg = lane >> 4;

    const short* Qbase = Qb + ((size_t)bh * SS + qt * 128 + w * 32) * DK;
    s16x8 qF[2][2];
    #pragma unroll
    for (int f = 0; f < 2; f++) {
        qF[f][0] = *(const s16x8*)(Qbase + (f * 16 + lr) * DK + lg * 8);
        qF[f][1] = *(const s16x8*)(Qbase + (f * 16 + lr) * DK + 32 + lg * 8);
    }
    s16x8 onesF;
    #pragma unroll
    for (int i = 0; i < 8; i++) onesF[i] = (short)0x3F80;     // bf16 1.0

    const char* Kbase = (const char*)(Kb + (size_t)bh * SS * DK);
    const char* Vbase = (const char*)(VT2 + (size_t)bh * DK * SS);
    const int rk0 = w * 16 + (lane >> 3), rk1 = rk0 + 8;
    const int gl = lane & 7;
    const char* pK0 = Kbase + rk0 * 128 + ((gl ^ (rk0 & 7)) << 4);
    const char* pK1 = Kbase + rk1 * 128 + ((gl ^ (rk1 & 7)) << 4);
    const char* pV0 = Vbase + rk0 * (SS * 2) + ((gl ^ (rk0 & 7)) << 4);
    const char* pV1 = Vbase + rk1 * (SS * 2) + ((gl ^ (rk1 & 7)) << 4);

    const int x7 = lr & 7;
    const int gx0 = (lg ^ x7) << 4;
    const int gx1 = ((4 + lg) ^ x7) << 4;

    f32x4 acc[2][4] = {};
    f32x4 accs[2] = {};
    float mrun[2] = {-1e30f, -1e30f};

    {
        char* d = smem[0];
        gll16(pK0, d + w * 2048);
        gll16(pK1, d + w * 2048 + 1024);
        gll16(pV0, d + 8192 + w * 2048);
        gll16(pV1, d + 8192 + w * 2048 + 1024);
    }
    __syncthreads();

    int cur = 0;
    for (int kt = 0; kt < SS; kt += 64) {
        if (kt + 64 < SS) {
            char* d = smem[cur ^ 1];
            const int oK = (kt + 64) * 128, oV = (kt + 64) * 2;
            gll16(pK0 + oK, d + w * 2048);
            gll16(pK1 + oK, d + w * 2048 + 1024);
            gll16(pV0 + oV, d + 8192 + w * 2048);
            gll16(pV1 + oV, d + 8192 + w * 2048 + 1024);
        }
        const char* bs = smem[cur];

        s16x8 kA[4][2];
        #pragma unroll
        for (int kg = 0; kg < 4; kg++) {
            const char* rp = bs + (kg * 16 + lr) * 128;
            kA[kg][0] = *(const s16x8*)(rp + gx0);
            kA[kg][1] = *(const s16x8*)(rp + gx1);
        }
        f32x4 st[2][4];
        __builtin_amdgcn_s_setprio(1);
        #pragma unroll
        for (int f = 0; f < 2; f++)
            #pragma unroll
            for (int kg = 0; kg < 4; kg++) {
                f32x4 z = {};
                z = __builtin_amdgcn_mfma_f32_16x16x32_bf16(kA[kg][0], qF[f][0], z, 0, 0, 0);
                st[f][kg] = __builtin_amdgcn_mfma_f32_16x16x32_bf16(kA[kg][1], qF[f][1], z, 0, 0, 0);
            }
        __builtin_amdgcn_s_setprio(0);

        s16x8 pb[2][2];
        #pragma unroll
        for (int f = 0; f < 2; f++) {
            float tmax = fmaxf(fmaxf(fmaxf(fmaxf(st[f][0][0], st[f][0][1]), fmaxf(st[f][0][2], st[f][0][3])),
                                     fmaxf(fmaxf(st[f][1][0], st[f][1][1]), fmaxf(st[f][1][2], st[f][1][3]))),
                               fmaxf(fmaxf(fmaxf(st[f][2][0], st[f][2][1]), fmaxf(st[f][2][2], st[f][2][3])),
                                     fmaxf(fmaxf(st[f][3][0], st[f][3][1]), fmaxf(st[f][3][2], st[f][3][3]))));
            tmax = fmaxf(tmax, __shfl_xor(tmax, 16));
            tmax = fmaxf(tmax, __shfl_xor(tmax, 32));
            if (!__all(tmax <= mrun[f] + 8.0f)) {        // defer-max (T13)
                float mnew = fmaxf(mrun[f], tmax);
                float alpha = fexp2(mrun[f] - mnew);
                mrun[f] = mnew;
                #pragma unroll
                for (int rg = 0; rg < 4; rg++) accs[f][rg] *= alpha;
                #pragma unroll
                for (int vt = 0; vt < 4; vt++)
                    #pragma unroll
                    for (int rg = 0; rg < 4; rg++) acc[f][vt][rg] *= alpha;
            }
            float p[4][4];
            #pragma unroll
            for (int kg = 0; kg < 4; kg++)
                #pragma unroll
                for (int rg = 0; rg < 4; rg++)
                    p[kg][rg] = fexp2(st[f][kg][rg] - mrun[f]);
            #pragma unroll
            for (int ks = 0; ks < 2; ks++) {
                union { s16x8 v; unsigned u[4]; } U;
                U.u[0] = pk2(p[2 * ks][1],     p[2 * ks][0]);
                U.u[1] = pk2(p[2 * ks][3],     p[2 * ks][2]);
                U.u[2] = pk2(p[2 * ks + 1][1], p[2 * ks + 1][0]);
                U.u[3] = pk2(p[2 * ks + 1][3], p[2 * ks + 1][2]);
                pb[f][ks] = U.v;
            }
        }

        __builtin_amdgcn_s_setprio(1);
        #pragma unroll
        for (int f = 0; f < 2; f++) {        // row-sum via ones-column
            accs[f] = __builtin_amdgcn_mfma_f32_16x16x32_bf16(onesF, pb[f][0], accs[f], 0, 0, 0);
            accs[f] = __builtin_amdgcn_mfma_f32_16x16x32_bf16(onesF, pb[f][1], accs[f], 0, 0, 0);
        }
        #pragma unroll
        for (int vt = 0; vt < 4; vt++) {
            const char* rp = bs + 8192 + (vt * 16 + lr) * 128;
            s16x8 vA0 = *(const s16x8*)(rp + gx0);
            s16x8 vA1 = *(const s16x8*)(rp + gx1);
            #pragma unroll
            for (int f = 0; f < 2; f++) {
                acc[f][vt] = __builtin_amdgcn_mfma_f32_16x16x32_bf16(vA0, pb[f][0], acc[f][vt], 0, 0, 0);
                acc[f][vt] = __builtin_amdgcn_mfma_f32_16x16x32_bf16(vA1, pb[f][1], acc[f][vt], 0, 0, 0);
            }
        }
        __builtin_amdgcn_s_setprio(0);
        __syncthreads();
        cur ^= 1;
    }

    char* ods = smem[0] + w * 4096;
    float inv[2] = {1.0f / accs[0][0], 1.0f / accs[1][0]};
    #pragma unroll
    for (int f = 0; f < 2; f++)
        #pragma unroll
        for (int vt = 0; vt < 4; vt++)
            #pragma unroll
            for (int rg = 0; rg < 4; rg++)
                *(short*)(ods + (f * 16 + lr) * 128 + (vt * 16 + lg * 4 + rg) * 2) =
                    f2bf(acc[f][vt][rg] * inv[f]);
    __syncthreads();
    {
        int r = lane >> 1, hb = lane & 1;
        const char* srow = smem[0] + w * 4096 + r * 128 + hb * 64;
        int token = b * SS + qt * 128 + w * 32 + r;
        char* dst = (char*)(cat + (size_t)token * 1024 + h * 64 + hb * 32);
        #pragma unroll
        for (int i = 0; i < 4; i++)
            *(s16x8*)(dst + i * 16) = *(const s16x8*)(srow + i * 16);
    }
}

// ---------------- LayerNorm ----------------
__global__ __launch_bounds__(256) void k_ln(const float* __restrict__ Y,
                                            const float* __restrict__ gamma,
                                            const float* __restrict__ beta,
                                            float* __restrict__ out) {
    const int row = blockIdx.x;
    const int t = threadIdx.x;
    const float* y = Y + (size_t)row * 1024;
    f32x4 v = reinterpret_cast<const f32x4*>(y)[t];
    float s = v[0] + v[1] + v[2] + v[3];
    float s2 = v[0] * v[0] + v[1] * v[1] + v[2] * v[2] + v[3] * v[3];
    #pragma unroll
    for (int off = 32; off; off >>= 1) {
        s += __shfl_xor(s, off);
        s2 += __shfl_xor(s2, off);
    }
    __shared__ float red[8];
    int w = t >> 6, lane = t & 63;
    if (lane == 0) { red[w] = s; red[4 + w] = s2; }
    __syncthreads();
    float S = red[0] + red[1] + red[2] + red[3];
    float S2 = red[4] + red[5] + red[6] + red[7];
    float mu = S * (1.f / 1024.f);
    float var = S2 * (1.f / 1024.f) - mu * mu;
    float rs = rsqrtf(var + LN_EPS);
    f32x4 g = reinterpret_cast<const f32x4*>(gamma)[t];
    f32x4 be = reinterpret_cast<const f32x4*>(beta)[t];
    f32x4 o;
    #pragma unroll
    for (int i = 0; i < 4; i++) o[i] = (v[i] - mu) * rs * g[i] + be[i];
    reinterpret_cast<f32x4*>(out + (size_t)row * 1024)[t] = o;
}

// ---------------- launch ----------------
extern "C" void kernel_launch(void* const* d_in, const int* in_sizes, int n_in,
                              void* d_out, int out_size, void* d_ws, size_t ws_size,
                              hipStream_t stream) {
    const float* x    = (const float*)d_in[0];
    const float* Wq   = (const float*)d_in[1];
    const float* bq   = (const float*)d_in[2];
    const float* Wk   = (const float*)d_in[3];
    const float* bk   = (const float*)d_in[4];
    const float* Wv   = (const float*)d_in[5];
    const float* bv   = (const float*)d_in[6];
    const float* Wfc  = (const float*)d_in[7];
    const float* bfc  = (const float*)d_in[8];
    const float* gamma= (const float*)d_in[9];
    const float* beta = (const float*)d_in[10];
    float* out = (float*)d_out;

    char* p = (char*)d_ws;
    short* xb   = (short*)p; p += (size_t)NTOK * 1024 * 2;
    short* WT   = (short*)p; p += (size_t)3072 * 1024 * 2;
    short* WfcT = (short*)p; p += (size_t)1024 * 1024 * 2;
    short* Qb   = (short*)p; p += (size_t)64 * SS * 64 * 2;
    short* Kb   = (short*)p; p += (size_t)64 * SS * 64 * 2;
    short* Vb   = (short*)p; p += (size_t)64 * SS * 64 * 2;
    short* VTb  = (short*)p; p += (size_t)64 * 64 * SS * 2;
    short* cat  = (short*)p; p += (size_t)NTOK * 1024 * 2;
    float* Y    = (float*)Qb;  // aliases Qb+Kb (dead after k_attn2)

    k_cast_x     <<<NTOK * 1024 / 4 / 256, 256, 0, stream>>>(x, xb);
    k_conv_wqkv_t<<<dim3(64, 48), 256, 0, stream>>>(Wq, Wk, Wv, WT);
    k_conv_wfc_t <<<1024, 256, 0, stream>>>(Wfc, WfcT);
    k_gemm2<0>   <<<dim3(24, 64), 256, 0, stream>>>(xb, WT, bq, bk, bv, nullptr, Qb, Kb, Vb, nullptr);
    k_transpose_v<<<dim3(SS / 64, 64), 256, 0, stream>>>(Vb, VTb);
    k_attn2      <<<dim3(SS / 128, 64), 256, 0, stream>>>(Qb, Kb, VTb, cat);
    k_gemm2<1>   <<<dim3(8, 64), 256, 0, stream>>>(cat, WfcT, nullptr, nullptr, nullptr, bfc, nullptr, nullptr, nullptr, Y);
    k_ln         <<<NTOK, 256, 0, stream>>>(Y, gamma, beta, out);
}

// Round 6
// 262.628 us; speedup vs baseline: 3.3023x; 1.0814x over previous
//
#include <hip/hip_runtime.h>

#define NH 16
#define DMODEL 1024
#define DK 64
#define DV 64
#define BB 4
#define SS 2048
#define NTOK (BB*SS)
#define LN_EPS 1e-5f

typedef __attribute__((ext_vector_type(4))) float f32x4;
typedef __attribute__((ext_vector_type(8))) short s16x8;
typedef __attribute__((ext_vector_type(4))) short s16x4;

__device__ __forceinline__ short f2bf(float f) {
    union { float f; unsigned u; } a; a.f = f;
    unsigned r = a.u + 0x7FFFu + ((a.u >> 16) & 1u);
    return (short)(r >> 16);
}
// pack two floats -> (bf16(a)<<16)|bf16(b), round-half-up
__device__ __forceinline__ unsigned pk2(float a, float b) {
    union { float f; unsigned u; } x, y; x.f = a; y.f = b;
    return __builtin_amdgcn_perm(x.u + 0x8000u, y.u + 0x8000u, 0x07060302u);
}
// bare v_exp_f32 (2^x): avoids __ocml_exp2_f32 libcall; FTZ on underflow is desired
__device__ __forceinline__ float fexp2(float x) { return __builtin_amdgcn_exp2f(x); }
__device__ __forceinline__ void gll16(const void* g, void* l) {
    __builtin_amdgcn_global_load_lds(
        (const __attribute__((address_space(1))) unsigned int*)g,
        (__attribute__((address_space(3))) unsigned int*)l, 16, 0, 0);
}

// ---------------- K0: cast x ----------------
__global__ void k_cast_x(const float* __restrict__ x, short* __restrict__ xb) {
    int i = blockIdx.x * blockDim.x + threadIdx.x;
    f32x4 v = reinterpret_cast<const f32x4*>(x)[i];
    s16x4 o;
    o[0] = f2bf(v[0]); o[1] = f2bf(v[1]); o[2] = f2bf(v[2]); o[3] = f2bf(v[3]);
    reinterpret_cast<s16x4*>(xb)[i] = o;
}

// ---------------- tiled transpose-cast: Wq/Wk/Wv [h][d][kk] -> WT[mat*1024+h*64+kk][d]
__global__ __launch_bounds__(256) void k_conv_wqkv_t(const float* __restrict__ Wq,
                                                     const float* __restrict__ Wk,
                                                     const float* __restrict__ Wv,
                                                     short* __restrict__ WT) {
    __shared__ float tile[64][17];
    const int mh = blockIdx.y;
    const int mat = mh >> 4, h = mh & 15;
    const int dt = blockIdx.x >> 2, kt = blockIdx.x & 3;
    const float* src = (mat == 0 ? Wq : (mat == 1 ? Wk : Wv));
    const int t = threadIdx.x;
    #pragma unroll
    for (int p = 0; p < 4; p++) {
        int d = p * 16 + (t >> 4), kk = t & 15;
        tile[d][kk] = src[((size_t)h * 1024 + dt * 64 + d) * 64 + kt * 16 + kk];
    }
    __syncthreads();
    #pragma unroll
    for (int p = 0; p < 4; p++) {
        int kk = p * 4 + (t >> 6), d = t & 63;
        WT[((size_t)mat * 1024 + h * 64 + kt * 16 + kk) * 1024 + dt * 64 + d] = f2bf(tile[d][kk]);
    }
}

__global__ __launch_bounds__(256) void k_conv_wfc_t(const float* __restrict__ Wfc,
                                                    short* __restrict__ WfcT) {
    __shared__ float tile[64][17];
    const int ct = blockIdx.x >> 6, nt = blockIdx.x & 63;
    const int t = threadIdx.x;
    #pragma unroll
    for (int p = 0; p < 4; p++) {
        int c = p * 16 + (t >> 4), n = t & 15;
        tile[c][n] = Wfc[((size_t)ct * 64 + c) * 1024 + nt * 16 + n];
    }
    __syncthreads();
    #pragma unroll
    for (int p = 0; p < 4; p++) {
        int n = p * 4 + (t >> 6), c = t & 63;
        WfcT[((size_t)nt * 16 + n) * 1024 + ct * 64 + c] = f2bf(tile[c][n]);
    }
}

// ---------------- GEMM (m97 structure, BK=64): C[M,N] = A[M,1024] * BT[N,1024]^T
template<int MODE>
__global__ __launch_bounds__(256) void k_gemm2(const short* __restrict__ A,
                                               const short* __restrict__ BT,
                                               const float* __restrict__ bq,
                                               const float* __restrict__ bk,
                                               const float* __restrict__ bv,
                                               const float* __restrict__ bfc,
                                               short* __restrict__ Qb,
                                               short* __restrict__ Kb,
                                               short* __restrict__ Vb,
                                               float* __restrict__ Y) {
    __shared__ short sA[128][64];
    __shared__ short sB[128][64];
    const int gm0 = blockIdx.y * 128, gn0 = blockIdx.x * 128;
    const int t = threadIdx.x, lane = t & 63, w = t >> 6;
    const int wm = w >> 1, wn = w & 1;
    const int lr = lane & 15, lg = lane >> 4;

    f32x4 acc[4][4] = {};

    // staging: per call c (0..3), thread t loads 16B of row c*32 + (t>>3), granule t&7 (src-swizzled)
    const int lrow = t >> 3, gl = t & 7;
    const int sgx = (gl ^ (lrow & 7)) << 3;         // shorts
    const short* pa = A  + (size_t)(gm0 + lrow) * 1024 + sgx;
    const short* pb = BT + (size_t)(gn0 + lrow) * 1024 + sgx;
    char* dA = (char*)sA + w * 1024;
    char* dB = (char*)sB + w * 1024;

    // read-side swizzled granule byte offsets per k-slice
    const int x7 = lr & 7;
    const int gx0 = (lg ^ x7) << 4;
    const int gx1 = ((4 + lg) ^ x7) << 4;

    for (int k0 = 0; k0 < 1024; k0 += 64) {
        #pragma unroll
        for (int c = 0; c < 4; c++) {
            gll16(pa + (size_t)c * 32768 + k0, dA + c * 4096);
            gll16(pb + (size_t)c * 32768 + k0, dB + c * 4096);
        }
        __syncthreads();
        s16x8 aF[2][4], bF[2][4];
        #pragma unroll
        for (int i = 0; i < 4; i++) {
            const char* rpa = (char*)sA + (wm * 64 + i * 16 + lr) * 128;
            const char* rpb = (char*)sB + (wn * 64 + i * 16 + lr) * 128;
            aF[0][i] = *(const s16x8*)(rpa + gx0);
            aF[1][i] = *(const s16x8*)(rpa + gx1);
            bF[0][i] = *(const s16x8*)(rpb + gx0);
            bF[1][i] = *(const s16x8*)(rpb + gx1);
        }
        __builtin_amdgcn_s_setprio(1);
        #pragma unroll
        for (int kk = 0; kk < 2; kk++)
            #pragma unroll
            for (int i = 0; i < 4; i++)
                #pragma unroll
                for (int j = 0; j < 4; j++)
                    acc[i][j] = __builtin_amdgcn_mfma_f32_16x16x32_bf16(aF[kk][i], bF[kk][j], acc[i][j], 0, 0, 0);
        __builtin_amdgcn_s_setprio(0);
        __syncthreads();
    }

    #pragma unroll
    for (int i = 0; i < 4; i++) {
        #pragma unroll
        for (int j = 0; j < 4; j++) {
            #pragma unroll
            for (int rg = 0; rg < 4; rg++) {
                int m = gm0 + wm * 64 + i * 16 + lg * 4 + rg;
                int n = gn0 + wn * 64 + j * 16 + lr;
                float val = acc[i][j][rg];
                if (MODE == 0) {
                    int b = m >> 11, s = m & 2047;
                    if (n < 1024) {
                        int h = n >> 6, kk = n & 63;
                        val = (val + bq[n]) * 0.18033688011112042f;  // (1/8)*log2(e)
                        Qb[((size_t)(b * NH + h) * SS + s) * DK + kk] = f2bf(val);
                    } else if (n < 2048) {
                        int n2 = n - 1024; int h = n2 >> 6, kk = n2 & 63;
                        Kb[((size_t)(b * NH + h) * SS + s) * DK + kk] = f2bf(val + bk[n2]);
                    } else {
                        int n2 = n - 2048; int h = n2 >> 6, kk = n2 & 63;
                        Vb[((size_t)(b * NH + h) * SS + s) * DK + kk] = f2bf(val + bv[n2]);
                    }
                } else {
                    Y[(size_t)m * 1024 + n] = val + bfc[n];
                }
            }
        }
    }
}

// ---------------- V transpose + PV-fragment permute ----------------
__global__ __launch_bounds__(256) void k_transpose_v(const short* __restrict__ Vb,
                                                     short* __restrict__ VT) {
    __shared__ short tile[64][65];
    const int bh = blockIdx.y, s0 = blockIdx.x * 64;
    const short* src = Vb + ((size_t)bh * SS + s0) * 64;
    short* dst = VT + (size_t)bh * 64 * SS;
    const int t = threadIdx.x;
    {
        int r = t >> 2, c0 = (t & 3) * 16;
        s16x8 v0 = *reinterpret_cast<const s16x8*>(&src[r * 64 + c0]);
        s16x8 v1 = *reinterpret_cast<const s16x8*>(&src[r * 64 + c0 + 8]);
        #pragma unroll
        for (int i = 0; i < 8; i++) { tile[r][c0 + i] = v0[i]; tile[r][c0 + 8 + i] = v1[i]; }
    }
    __syncthreads();
    {
        int vv = t >> 2, so = (t & 3) * 16;
        int b32 = so >> 5, half = (so >> 4) & 1;
        short* drow = dst + (size_t)vv * SS + s0 + b32 * 32 + half * 4;
        #pragma unroll
        for (int lgp = 0; lgp < 4; lgp++) {
            s16x4 c;
            #pragma unroll
            for (int i = 0; i < 4; i++) c[i] = tile[b32 * 32 + half * 16 + lgp * 4 + i][vv];
            *reinterpret_cast<s16x4*>(drow + lgp * 8) = c;
        }
    }
}

// ---------------- Flash attention ----------------
__global__ __launch_bounds__(256) void k_attn2(const short* __restrict__ Qb,
                                               const short* __restrict__ Kb,
                                               const short* __restrict__ VT2,
                                               short* __restrict__ cat) {
    __shared__ char smem[2][16384];
    // XCD-bijective swizzle: each XCD gets 8 consecutive bh (K+V = 4MB = L2)
    const int fid = blockIdx.x + blockIdx.y * gridDim.x;      // 0..1023
    const int swz = ((fid & 7) << 7) | (fid >> 3);
    const int qt = swz & 15, bh = swz >> 4;
    const int b = bh >> 4, h = bh & 15;
    const int t = threadIdx.x, lane = t & 63, w = t >> 6;
    const int lr = lane & 15, lg = lane >> 4;

    const short* Qbase = Qb + ((size_t)bh * SS + qt * 128 + w * 32) * DK;
    s16x8 qF[2][2];
    #pragma unroll
    for (int f = 0; f < 2; f++) {
        qF[f][0] = *(const s16x8*)(Qbase + (f * 16 + lr) * DK + lg * 8);
        qF[f][1] = *(const s16x8*)(Qbase + (f * 16 + lr) * DK + 32 + lg * 8);
    }
    s16x8 onesF;
    #pragma unroll
    for (int i = 0; i < 8; i++) onesF[i] = (short)0x3F80;     // bf16 1.0

    const char* Kbase = (const char*)(Kb + (size_t)bh * SS * DK);
    const char* Vbase = (const char*)(VT2 + (size_t)bh * DK * SS);
    const int rk0 = w * 16 + (lane >> 3), rk1 = rk0 + 8;
    const int gl = lane & 7;
    const char* pK0 = Kbase + rk0 * 128 + ((gl ^ (rk0 & 7)) << 4);
    const char* pK1 = Kbase + rk1 * 128 + ((gl ^ (rk1 & 7)) << 4);
    const char* pV0 = Vbase + rk0 * (SS * 2) + ((gl ^ (rk0 & 7)) << 4);
    const char* pV1 = Vbase + rk1 * (SS * 2) + ((gl ^ (rk1 & 7)) << 4);

    const int x7 = lr & 7;
    const int gx0 = (lg ^ x7) << 4;
    const int gx1 = ((4 + lg) ^ x7) << 4;

    f32x4 acc[2][4] = {};
    f32x4 accs[2] = {};
    float mrun[2] = {-1e30f, -1e30f};

    {
        char* d = smem[0];
        gll16(pK0, d + w * 2048);
        gll16(pK1, d + w * 2048 + 1024);
        gll16(pV0, d + 8192 + w * 2048);
        gll16(pV1, d + 8192 + w * 2048 + 1024);
    }
    __syncthreads();

    int cur = 0;
    for (int kt = 0; kt < SS; kt += 64) {
        if (kt + 64 < SS) {
            char* d = smem[cur ^ 1];
            const int oK = (kt + 64) * 128, oV = (kt + 64) * 2;
            gll16(pK0 + oK, d + w * 2048);
            gll16(pK1 + oK, d + w * 2048 + 1024);
            gll16(pV0 + oV, d + 8192 + w * 2048);
            gll16(pV1 + oV, d + 8192 + w * 2048 + 1024);
        }
        const char* bs = smem[cur];

        s16x8 kA[4][2];
        #pragma unroll
        for (int kg = 0; kg < 4; kg++) {
            const char* rp = bs + (kg * 16 + lr) * 128;
            kA[kg][0] = *(const s16x8*)(rp + gx0);
            kA[kg][1] = *(const s16x8*)(rp + gx1);
        }
        f32x4 st[2][4];
        __builtin_amdgcn_s_setprio(1);
        #pragma unroll
        for (int f = 0; f < 2; f++)
            #pragma unroll
            for (int kg = 0; kg < 4; kg++) {
                f32x4 z = {};
                z = __builtin_amdgcn_mfma_f32_16x16x32_bf16(kA[kg][0], qF[f][0], z, 0, 0, 0);
                st[f][kg] = __builtin_amdgcn_mfma_f32_16x16x32_bf16(kA[kg][1], qF[f][1], z, 0, 0, 0);
            }
        __builtin_amdgcn_s_setprio(0);

        s16x8 pb[2][2];
        #pragma unroll
        for (int f = 0; f < 2; f++) {
            float tmax = fmaxf(fmaxf(fmaxf(fmaxf(st[f][0][0], st[f][0][1]), fmaxf(st[f][0][2], st[f][0][3])),
                                     fmaxf(fmaxf(st[f][1][0], st[f][1][1]), fmaxf(st[f][1][2], st[f][1][3]))),
                               fmaxf(fmaxf(fmaxf(st[f][2][0], st[f][2][1]), fmaxf(st[f][2][2], st[f][2][3])),
                                     fmaxf(fmaxf(st[f][3][0], st[f][3][1]), fmaxf(st[f][3][2], st[f][3][3]))));
            tmax = fmaxf(tmax, __shfl_xor(tmax, 16));
            tmax = fmaxf(tmax, __shfl_xor(tmax, 32));
            if (!__all(tmax <= mrun[f] + 8.0f)) {        // defer-max (T13)
                float mnew = fmaxf(mrun[f], tmax);
                float alpha = fexp2(mrun[f] - mnew);
                mrun[f] = mnew;
                #pragma unroll
                for (int rg = 0; rg < 4; rg++) accs[f][rg] *= alpha;
                #pragma unroll
                for (int vt = 0; vt < 4; vt++)
                    #pragma unroll
                    for (int rg = 0; rg < 4; rg++) acc[f][vt][rg] *= alpha;
            }
            float p[4][4];
            #pragma unroll
            for (int kg = 0; kg < 4; kg++)
                #pragma unroll
                for (int rg = 0; rg < 4; rg++)
                    p[kg][rg] = fexp2(st[f][kg][rg] - mrun[f]);
            #pragma unroll
            for (int ks = 0; ks < 2; ks++) {
                union { s16x8 v; unsigned u[4]; } U;
                U.u[0] = pk2(p[2 * ks][1],     p[2 * ks][0]);
                U.u[1] = pk2(p[2 * ks][3],     p[2 * ks][2]);
                U.u[2] = pk2(p[2 * ks + 1][1], p[2 * ks + 1][0]);
                U.u[3] = pk2(p[2 * ks + 1][3], p[2 * ks + 1][2]);
                pb[f][ks] = U.v;
            }
        }

        __builtin_amdgcn_s_setprio(1);
        #pragma unroll
        for (int f = 0; f < 2; f++) {        // row-sum via ones-column
            accs[f] = __builtin_amdgcn_mfma_f32_16x16x32_bf16(onesF, pb[f][0], accs[f], 0, 0, 0);
            accs[f] = __builtin_amdgcn_mfma_f32_16x16x32_bf16(onesF, pb[f][1], accs[f], 0, 0, 0);
        }
        #pragma unroll
        for (int vt = 0; vt < 4; vt++) {
            const char* rp = bs + 8192 + (vt * 16 + lr) * 128;
            s16x8 vA0 = *(const s16x8*)(rp + gx0);
            s16x8 vA1 = *(const s16x8*)(rp + gx1);
            #pragma unroll
            for (int f = 0; f < 2; f++) {
                acc[f][vt] = __builtin_amdgcn_mfma_f32_16x16x32_bf16(vA0, pb[f][0], acc[f][vt], 0, 0, 0);
                acc[f][vt] = __builtin_amdgcn_mfma_f32_16x16x32_bf16(vA1, pb[f][1], acc[f][vt], 0, 0, 0);
            }
        }
        __builtin_amdgcn_s_setprio(0);
        __syncthreads();
        cur ^= 1;
    }

    char* ods = smem[0] + w * 4096;
    float inv[2] = {1.0f / accs[0][0], 1.0f / accs[1][0]};
    #pragma unroll
    for (int f = 0; f < 2; f++)
        #pragma unroll
        for (int vt = 0; vt < 4; vt++)
            #pragma unroll
            for (int rg = 0; rg < 4; rg++)
                *(short*)(ods + (f * 16 + lr) * 128 + (vt * 16 + lg * 4 + rg) * 2) =
                    f2bf(acc[f][vt][rg] * inv[f]);
    __syncthreads();
    {
        int r = lane >> 1, hb = lane & 1;
        const char* srow = smem[0] + w * 4096 + r * 128 + hb * 64;
        int token = b * SS + qt * 128 + w * 32 + r;
        char* dst = (char*)(cat + (size_t)token * 1024 + h * 64 + hb * 32);
        #pragma unroll
        for (int i = 0; i < 4; i++)
            *(s16x8*)(dst + i * 16) = *(const s16x8*)(srow + i * 16);
    }
}

// ---------------- LayerNorm ----------------
__global__ __launch_bounds__(256) void k_ln(const float* __restrict__ Y,
                                            const float* __restrict__ gamma,
                                            const float* __restrict__ beta,
                                            float* __restrict__ out) {
    const int row = blockIdx.x;
    const int t = threadIdx.x;
    const float* y = Y + (size_t)row * 1024;
    f32x4 v = reinterpret_cast<const f32x4*>(y)[t];
    float s = v[0] + v[1] + v[2] + v[3];
    float s2 = v[0] * v[0] + v[1] * v[1] + v[2] * v[2] + v[3] * v[3];
    #pragma unroll
    for (int off = 32; off; off >>= 1) {
        s += __shfl_xor(s, off);
        s2 += __shfl_xor(s2, off);
    }
    __shared__ float red[8];
    int w = t >> 6, lane = t & 63;
    if (lane == 0) { red[w] = s; red[4 + w] = s2; }
    __syncthreads();
    float S = red[0] + red[1] + red[2] + red[3];
    float S2 = red[4] + red[5] + red[6] + red[7];
    float mu = S * (1.f / 1024.f);
    float var = S2 * (1.f / 1024.f) - mu * mu;
    float rs = rsqrtf(var + LN_EPS);
    f32x4 g = reinterpret_cast<const f32x4*>(gamma)[t];
    f32x4 be = reinterpret_cast<const f32x4*>(beta)[t];
    f32x4 o;
    #pragma unroll
    for (int i = 0; i < 4; i++) o[i] = (v[i] - mu) * rs * g[i] + be[i];
    reinterpret_cast<f32x4*>(out + (size_t)row * 1024)[t] = o;
}

// ---------------- launch ----------------
extern "C" void kernel_launch(void* const* d_in, const int* in_sizes, int n_in,
                              void* d_out, int out_size, void* d_ws, size_t ws_size,
                              hipStream_t stream) {
    const float* x    = (const float*)d_in[0];
    const float* Wq   = (const float*)d_in[1];
    const float* bq   = (const float*)d_in[2];
    const float* Wk   = (const float*)d_in[3];
    const float* bk   = (const float*)d_in[4];
    const float* Wv   = (const float*)d_in[5];
    const float* bv   = (const float*)d_in[6];
    const float* Wfc  = (const float*)d_in[7];
    const float* bfc  = (const float*)d_in[8];
    const float* gamma= (const float*)d_in[9];
    const float* beta = (const float*)d_in[10];
    float* out = (float*)d_out;

    char* p = (char*)d_ws;
    short* xb   = (short*)p; p += (size_t)NTOK * 1024 * 2;
    short* WT   = (short*)p; p += (size_t)3072 * 1024 * 2;
    short* WfcT = (short*)p; p += (size_t)1024 * 1024 * 2;
    short* Qb   = (short*)p; p += (size_t)64 * SS * 64 * 2;
    short* Kb   = (short*)p; p += (size_t)64 * SS * 64 * 2;
    short* Vb   = (short*)p; p += (size_t)64 * SS * 64 * 2;
    short* VTb  = (short*)p; p += (size_t)64 * 64 * SS * 2;
    short* cat  = (short*)p; p += (size_t)NTOK * 1024 * 2;
    float* Y    = (float*)Qb;  // aliases Qb+Kb (dead after k_attn2)

    k_cast_x     <<<NTOK * 1024 / 4 / 256, 256, 0, stream>>>(x, xb);
    k_conv_wqkv_t<<<dim3(64, 48), 256, 0, stream>>>(Wq, Wk, Wv, WT);
    k_conv_wfc_t <<<1024, 256, 0, stream>>>(Wfc, WfcT);
    k_gemm2<0>   <<<dim3(24, 64), 256, 0, stream>>>(xb, WT, bq, bk, bv, nullptr, Qb, Kb, Vb, nullptr);
    k_transpose_v<<<dim3(SS / 64, 64), 256, 0, stream>>>(Vb, VTb);
    k_attn2      <<<dim3(SS / 128, 64), 256, 0, stream>>>(Qb, Kb, VTb, cat);
    k_gemm2<1>   <<<dim3(8, 64), 256, 0, stream>>>(cat, WfcT, nullptr, nullptr, nullptr, bfc, nullptr, nullptr, nullptr, Y);
    k_ln         <<<NTOK, 256, 0, stream>>>(Y, gamma, beta, out);
}